// Round 14
// baseline (258.094 us; speedup 1.0000x reference)
//
#include <hip/hip_runtime.h>
#include <math.h>

#define S_LEN 2048
#define DMODEL 1024
#define NHEAD 16
#define HD 64
#define NBATCH 2

using short8  = __attribute__((ext_vector_type(8))) short;
using ushort8 = __attribute__((ext_vector_type(8))) unsigned short;
using floatx4 = __attribute__((ext_vector_type(4))) float;

__device__ __forceinline__ unsigned short f2b(float f) {
    unsigned int u = __float_as_uint(f);
    unsigned int r = (u + 0x7FFFu + ((u >> 16) & 1u)) >> 16;
    return (unsigned short)r;
}
__device__ __forceinline__ float b2f(unsigned short b) {
    return __uint_as_float(((unsigned int)b) << 16);
}

// async global->LDS, 16B per lane; LDS dest = wave-uniform base + lane*16
__device__ __forceinline__ void gll16(const void* g, void* l) {
    __builtin_amdgcn_global_load_lds(
        (const __attribute__((address_space(1))) unsigned int*)g,
        (__attribute__((address_space(3))) unsigned int*)l, 16, 0, 0);
}

// ---------------------------------------------------------------------------
// fp32 -> bf16 convert; z selects Q/K/V
// ---------------------------------------------------------------------------
__global__ __launch_bounds__(256)
void convert_bf16(const float* __restrict__ S0, const float* __restrict__ S1,
                  const float* __restrict__ S2,
                  unsigned short* __restrict__ D0, unsigned short* __restrict__ D1,
                  unsigned short* __restrict__ D2, int n4)
{
    const float* src = (blockIdx.z == 0) ? S0 : (blockIdx.z == 1) ? S1 : S2;
    unsigned short* dst = (blockIdx.z == 0) ? D0 : (blockIdx.z == 1) ? D1 : D2;
    int i = blockIdx.x * 256 + threadIdx.x;
    if (i < n4) {
        float4 v = ((const float4*)src)[i];
        ushort4 o;
        o.x = f2b(v.x); o.y = f2b(v.y); o.z = f2b(v.z); o.w = f2b(v.w);
        ((ushort4*)dst)[i] = o;
    }
}

// ---------------------------------------------------------------------------
__global__ __launch_bounds__(256)
void transpose_w(const float* __restrict__ W0, const float* __restrict__ W1,
                 const float* __restrict__ W2, const float* __restrict__ W3,
                 unsigned short* __restrict__ T0, unsigned short* __restrict__ T1,
                 unsigned short* __restrict__ T2, unsigned short* __restrict__ T3)
{
    __shared__ float t[64][65];
    const float* W; unsigned short* T;
    switch (blockIdx.z) {
        case 0: W = W0; T = T0; break;
        case 1: W = W1; T = T1; break;
        case 2: W = W2; T = T2; break;
        default: W = W3; T = T3; break;
    }
    const int tid = threadIdx.x;
    const int c0 = blockIdx.x * 64;
    const int r0 = blockIdx.y * 64;
    #pragma unroll
    for (int i = 0; i < 4; ++i) {
        int c = tid + i * 256;
        int r = c >> 4, off = (c & 15) * 4;
        float4 v = *(const float4*)(W + (size_t)(r0 + r) * DMODEL + c0 + off);
        t[r][off + 0] = v.x; t[r][off + 1] = v.y;
        t[r][off + 2] = v.z; t[r][off + 3] = v.w;
    }
    __syncthreads();
    #pragma unroll
    for (int i = 0; i < 4; ++i) {
        int c = tid + i * 256;
        int n = c >> 4, off = (c & 15) * 4;
        ushort4 o;
        o.x = f2b(t[off + 0][n]); o.y = f2b(t[off + 1][n]);
        o.z = f2b(t[off + 2][n]); o.w = f2b(t[off + 3][n]);
        *(ushort4*)(T + (size_t)(c0 + n) * DMODEL + r0 + off) = o;
    }
}

// ---------------------------------------------------------------------------
// QKV GEMM, tile 128x128, BK=64, global_load_lds staging with XOR swizzle.
// z==0/1 (Q/K): head-major [B,H,S,64]. z==2 (V): TRANSPOSED [B,H,64,S].
// ---------------------------------------------------------------------------
__global__ __launch_bounds__(256)
void gemm_qkv(const unsigned short* __restrict__ X0, const unsigned short* __restrict__ X1,
              const unsigned short* __restrict__ X2,
              const unsigned short* __restrict__ W0, const unsigned short* __restrict__ W1,
              const unsigned short* __restrict__ W2,
              const float* __restrict__ b0, const float* __restrict__ b1,
              const float* __restrict__ b2,
              unsigned short* __restrict__ o0, unsigned short* __restrict__ o1,
              unsigned short* __restrict__ o2)
{
    __shared__ unsigned short Xs[128 * 64];
    __shared__ unsigned short Ws[128 * 64];

    const unsigned short* X  = (blockIdx.z == 0) ? X0 : (blockIdx.z == 1) ? X1 : X2;
    const unsigned short* Wt = (blockIdx.z == 0) ? W0 : (blockIdx.z == 1) ? W1 : W2;
    const float* bias        = (blockIdx.z == 0) ? b0 : (blockIdx.z == 1) ? b1 : b2;
    unsigned short* outp     = (blockIdx.z == 0) ? o0 : (blockIdx.z == 1) ? o1 : o2;

    const int tid = threadIdx.x;
    const int lane = tid & 63, w = tid >> 6;
    const int l15 = lane & 15, l4 = lane >> 4;
    const int wr = w >> 1, wc = w & 1;
    const int row0 = blockIdx.y * 128;
    const int col0 = blockIdx.x * 128;

    const int srow = lane >> 3;
    const int sblk = (lane & 7) ^ srow;

    floatx4 acc[4][4] = {};

    for (int k0 = 0; k0 < DMODEL; k0 += 64) {
        __syncthreads();
        #pragma unroll
        for (int i = 0; i < 4; ++i)
            gll16(X + (size_t)(row0 + w * 32 + i * 8 + srow) * DMODEL + k0 + sblk * 8,
                  &Xs[(w * 32 + i * 8) * 64]);
        #pragma unroll
        for (int i = 0; i < 4; ++i)
            gll16(Wt + (size_t)(col0 + w * 32 + i * 8 + srow) * DMODEL + k0 + sblk * 8,
                  &Ws[(w * 32 + i * 8) * 64]);
        asm volatile("s_waitcnt vmcnt(0)" ::: "memory");
        __syncthreads();

        #pragma unroll
        for (int ks = 0; ks < 2; ++ks) {
            short8 a[4], b[4];
            #pragma unroll
            for (int m = 0; m < 4; ++m) {
                const int r = wr * 64 + m * 16 + l15;
                a[m] = *(const short8*)&Xs[r * 64 + (((ks * 4 + l4) ^ (r & 7)) << 3)];
            }
            #pragma unroll
            for (int n = 0; n < 4; ++n) {
                const int r = wc * 64 + n * 16 + l15;
                b[n] = *(const short8*)&Ws[r * 64 + (((ks * 4 + l4) ^ (r & 7)) << 3)];
            }
            #pragma unroll
            for (int m = 0; m < 4; ++m)
                #pragma unroll
                for (int n = 0; n < 4; ++n)
                    acc[m][n] = __builtin_amdgcn_mfma_f32_16x16x32_bf16(
                        a[m], b[n], acc[m][n], 0, 0, 0);
        }
    }

    float bl[4];
    #pragma unroll
    for (int n = 0; n < 4; ++n)
        bl[n] = bias[col0 + wc * 64 + n * 16 + l15];

    if (blockIdx.z != 2) {
        #pragma unroll
        for (int m = 0; m < 4; ++m)
            #pragma unroll
            for (int n = 0; n < 4; ++n) {
                const int gc = col0 + wc * 64 + n * 16 + l15;
                const int h = gc >> 6, d = gc & 63;
                #pragma unroll
                for (int reg = 0; reg < 4; ++reg) {
                    const int gr = row0 + wr * 64 + m * 16 + l4 * 4 + reg;
                    const int bb = gr >> 11, s = gr & 2047;
                    outp[(((size_t)bb * NHEAD + h) * S_LEN + s) * HD + d] =
                        f2b(acc[m][n][reg] + bl[n]);
                }
            }
    } else {
        #pragma unroll
        for (int m = 0; m < 4; ++m)
            #pragma unroll
            for (int n = 0; n < 4; ++n) {
                const int gc = col0 + wc * 64 + n * 16 + l15;
                const int h = gc >> 6, d = gc & 63;
                const int s0 = row0 + wr * 64 + m * 16 + l4 * 4;
                const int bb = s0 >> 11, sr = s0 & 2047;
                ushort4 pk;
                pk.x = f2b(acc[m][n][0] + bl[n]);
                pk.y = f2b(acc[m][n][1] + bl[n]);
                pk.z = f2b(acc[m][n][2] + bl[n]);
                pk.w = f2b(acc[m][n][3] + bl[n]);
                *(ushort4*)(outp + (((size_t)bb * NHEAD + h) * HD + d) * S_LEN + sr) = pk;
            }
    }
}

// ---------------------------------------------------------------------------
// Output projection GEMM, tile 128x64 -> grid (16,32)=512 wg = 2 blocks/CU.
// ---------------------------------------------------------------------------
__global__ __launch_bounds__(256)
void gemm_out(const unsigned short* __restrict__ X, const unsigned short* __restrict__ Wt,
              const float* __restrict__ bias, float* __restrict__ out)
{
    __shared__ unsigned short Xs[128 * 64];
    __shared__ unsigned short Ws[64 * 64];

    const int tid = threadIdx.x;
    const int lane = tid & 63, w = tid >> 6;
    const int l15 = lane & 15, l4 = lane >> 4;
    const int wr = w >> 1, wc = w & 1;
    const int row0 = blockIdx.y * 128;
    const int col0 = blockIdx.x * 64;

    const int srow = lane >> 3;
    const int sblk = (lane & 7) ^ srow;

    floatx4 acc[4][2] = {};

    for (int k0 = 0; k0 < DMODEL; k0 += 64) {
        __syncthreads();
        #pragma unroll
        for (int i = 0; i < 4; ++i)
            gll16(X + (size_t)(row0 + w * 32 + i * 8 + srow) * DMODEL + k0 + sblk * 8,
                  &Xs[(w * 32 + i * 8) * 64]);
        #pragma unroll
        for (int i = 0; i < 2; ++i)
            gll16(Wt + (size_t)(col0 + w * 16 + i * 8 + srow) * DMODEL + k0 + sblk * 8,
                  &Ws[(w * 16 + i * 8) * 64]);
        asm volatile("s_waitcnt vmcnt(0)" ::: "memory");
        __syncthreads();

        #pragma unroll
        for (int ks = 0; ks < 2; ++ks) {
            short8 a[4], b[2];
            #pragma unroll
            for (int m = 0; m < 4; ++m) {
                const int r = wr * 64 + m * 16 + l15;
                a[m] = *(const short8*)&Xs[r * 64 + (((ks * 4 + l4) ^ (r & 7)) << 3)];
            }
            #pragma unroll
            for (int n = 0; n < 2; ++n) {
                const int r = wc * 32 + n * 16 + l15;
                b[n] = *(const short8*)&Ws[r * 64 + (((ks * 4 + l4) ^ (r & 7)) << 3)];
            }
            #pragma unroll
            for (int m = 0; m < 4; ++m)
                #pragma unroll
                for (int n = 0; n < 2; ++n)
                    acc[m][n] = __builtin_amdgcn_mfma_f32_16x16x32_bf16(
                        a[m], b[n], acc[m][n], 0, 0, 0);
        }
    }

    float bl[2];
    #pragma unroll
    for (int n = 0; n < 2; ++n)
        bl[n] = bias[col0 + wc * 32 + n * 16 + l15];

    #pragma unroll
    for (int m = 0; m < 4; ++m)
        #pragma unroll
        for (int n = 0; n < 2; ++n) {
            const int gc = col0 + wc * 32 + n * 16 + l15;
            #pragma unroll
            for (int reg = 0; reg < 4; ++reg) {
                const int gr = row0 + wr * 64 + m * 16 + l4 * 4 + reg;
                out[(size_t)gr * DMODEL + gc] = acc[m][n][reg] + bl[n];
            }
        }
}

// ---------------------------------------------------------------------------
// Attention stats: 128 q-rows/block, grid 512. QK^T + exp row-sums only.
// K dbuf + counted vmcnt. Writes nl2 = -log2(rowsum) to workspace.
// Each staged K tile serves 2x the rows of the 64-row write kernel.
// ---------------------------------------------------------------------------
__global__ __launch_bounds__(256)
void attn_stats(const unsigned short* __restrict__ qg, const unsigned short* __restrict__ kg,
                float* __restrict__ nl2g)
{
    __shared__ unsigned short Ks[2 * 64 * 64];

    const int tid = threadIdx.x;
    const int lane = tid & 63, w = tid >> 6;
    const int l15 = lane & 15, l4 = lane >> 4;

    const int i0 = blockIdx.x;              // 0..511
    const int local = i0 >> 3;               // 0..63
    const int bh = (i0 & 7) * 4 + (local & 3);
    const int qx = local >> 2;                // 0..15
    const int qb = (bh & 1) ? (15 - qx) : qx;
    const int row0 = qb * 128;

    const int srow = lane >> 3;
    const int sblk = (lane & 7) ^ srow;

    const float C2 = 0.18033688011112042f;   // 0.125 * log2(e)

    const unsigned short* qh = qg + (size_t)bh * S_LEN * HD;
    const unsigned short* kh = kg + (size_t)bh * S_LEN * HD;

    // wave w owns rows row0 + w*32 .. +31 (2 strips of 16)
    short8 qa[2][2];
    #pragma unroll
    for (int m = 0; m < 2; ++m)
        #pragma unroll
        for (int ks = 0; ks < 2; ++ks)
            qa[m][ks] = *(const short8*)(qh + (size_t)(row0 + w * 32 + m * 16 + l15) * HD
                                         + ks * 32 + l4 * 8);

    const int nt = 2 * qb + 2;

    #pragma unroll
    for (int i = 0; i < 2; ++i)
        gll16(kh + (size_t)(w * 16 + i * 8 + srow) * HD + sblk * 8,
              &Ks[(w * 16 + i * 8) * 64]);

    float lsum[2][4] = {};
    for (int jt = 0; jt < nt; ++jt) {
        const int cur = jt & 1;
        __syncthreads();
        if (jt + 1 < nt) {
            #pragma unroll
            for (int i = 0; i < 2; ++i)
                gll16(kh + (size_t)((jt + 1) * 64 + w * 16 + i * 8 + srow) * HD + sblk * 8,
                      &Ks[(cur ^ 1) * 4096 + (w * 16 + i * 8) * 64]);
            asm volatile("s_waitcnt vmcnt(2)" ::: "memory");
        } else {
            asm volatile("s_waitcnt vmcnt(0)" ::: "memory");
        }
        __syncthreads();

        floatx4 sf[2][4] = {};
        #pragma unroll
        for (int ks = 0; ks < 2; ++ks) {
            short8 kb[4];
            #pragma unroll
            for (int c = 0; c < 4; ++c) {
                const int r = c * 16 + l15;
                kb[c] = *(const short8*)&Ks[cur * 4096 + r * 64
                                            + (((ks * 4 + l4) ^ (r & 7)) << 3)];
            }
            #pragma unroll
            for (int m = 0; m < 2; ++m)
                #pragma unroll
                for (int c = 0; c < 4; ++c)
                    sf[m][c] = __builtin_amdgcn_mfma_f32_16x16x32_bf16(
                        qa[m][ks], kb[c], sf[m][c], 0, 0, 0);
        }

        #pragma unroll
        for (int m = 0; m < 2; ++m) {
            const int rbase = row0 + w * 32 + m * 16;
            if (jt * 64 + 63 <= rbase) {       // wave-uniform full tile
                #pragma unroll
                for (int c = 0; c < 4; ++c)
                    #pragma unroll
                    for (int reg = 0; reg < 4; ++reg)
                        lsum[m][reg] += exp2f(sf[m][c][reg] * C2);
            } else {
                #pragma unroll
                for (int c = 0; c < 4; ++c) {
                    const int jcol = jt * 64 + c * 16 + l15;
                    #pragma unroll
                    for (int reg = 0; reg < 4; ++reg) {
                        const int grow = rbase + l4 * 4 + reg;
                        lsum[m][reg] += (jcol <= grow) ? exp2f(sf[m][c][reg] * C2) : 0.f;
                    }
                }
            }
        }
    }

    #pragma unroll
    for (int m = 0; m < 2; ++m)
        #pragma unroll
        for (int reg = 0; reg < 4; ++reg) {
            float s = lsum[m][reg];
            #pragma unroll
            for (int off = 1; off < 16; off <<= 1)
                s += __shfl_xor(s, off);
            if (l15 == 0)
                nl2g[(size_t)bh * S_LEN + row0 + w * 32 + m * 16 + l4 * 4 + reg] =
                    -__log2f(s);
        }
}

// ---------------------------------------------------------------------------
// Attention write: 64 q-rows/block, grid 1024 = 4 blocks/CU. Single pass:
// QK^T (K gll16 dbuf, counted vmcnt), exp with precomputed nl2, Ps, NT P
// store, PV (V gll16 from transposed layout).
// ---------------------------------------------------------------------------
__global__ __launch_bounds__(256)
void attn_write(const unsigned short* __restrict__ qg, const unsigned short* __restrict__ kg,
                const unsigned short* __restrict__ vtg, const float* __restrict__ nl2g,
                float* __restrict__ attn, unsigned short* __restrict__ ctx)
{
    __shared__ unsigned short Ks[2 * 64 * 64];
    __shared__ unsigned short Vt[64 * 64];
    __shared__ unsigned short Ps[64 * 88];

    const int tid = threadIdx.x;
    const int lane = tid & 63, w = tid >> 6;
    const int l15 = lane & 15, l4 = lane >> 4;

    const int i0 = blockIdx.x;
    const int local = i0 >> 3;
    const int bh = (i0 & 7) * 4 + (local & 3);
    const int qx = local >> 2;
    const int qb = (bh & 1) ? (31 - qx) : qx;
    const int row0 = qb * 64;

    const int srow = lane >> 3;
    const int sblk = (lane & 7) ^ srow;

    const float C2 = 0.18033688011112042f;   // 0.125 * log2(e)

    const unsigned short* qh = qg + (size_t)bh * S_LEN * HD;
    const unsigned short* kh = kg + (size_t)bh * S_LEN * HD;
    const unsigned short* vth = vtg + (size_t)bh * HD * S_LEN;   // [d][s]
    float* attnh = attn + (size_t)bh * S_LEN * S_LEN;

    short8 qa[2];
    #pragma unroll
    for (int ks = 0; ks < 2; ++ks)
        qa[ks] = *(const short8*)(qh + (size_t)(row0 + w * 16 + l15) * HD + ks * 32 + l4 * 8);

    float nl2[4];
    {
        const float4 nv = *(const float4*)(nl2g + (size_t)bh * S_LEN + row0 + w * 16 + l4 * 4);
        nl2[0] = nv.x; nl2[1] = nv.y; nl2[2] = nv.z; nl2[3] = nv.w;
    }

    const int nt = qb + 1;

    #pragma unroll
    for (int i = 0; i < 2; ++i)
        gll16(kh + (size_t)(w * 16 + i * 8 + srow) * HD + sblk * 8,
              &Ks[(w * 16 + i * 8) * 64]);

    floatx4 o[4] = {};
    for (int jt = 0; jt < nt; ++jt) {
        const int buf = jt & 1;
        asm volatile("s_waitcnt vmcnt(0)" ::: "memory");   // K(jt) landed
        __syncthreads();                   // B: all PV(jt-1) done; K(jt) visible

        // stage V(jt) (FIFO-older than K(jt+1))
        #pragma unroll
        for (int i = 0; i < 2; ++i)
            gll16(vth + (size_t)(w * 16 + i * 8 + srow) * S_LEN + jt * 64 + sblk * 8,
                  &Vt[(w * 16 + i * 8) * 64]);
        if (jt + 1 < nt) {
            #pragma unroll
            for (int i = 0; i < 2; ++i)
                gll16(kh + (size_t)((jt + 1) * 64 + w * 16 + i * 8 + srow) * HD + sblk * 8,
                      &Ks[(buf ^ 1) * 4096 + (w * 16 + i * 8) * 64]);
        }

        floatx4 sf[4] = {};
        #pragma unroll
        for (int ks = 0; ks < 2; ++ks) {
            short8 kb[4];
            #pragma unroll
            for (int c = 0; c < 4; ++c) {
                const int r = c * 16 + l15;
                kb[c] = *(const short8*)&Ks[buf * 4096 + r * 64
                                            + (((ks * 4 + l4) ^ (r & 7)) << 3)];
            }
            #pragma unroll
            for (int c = 0; c < 4; ++c)
                sf[c] = __builtin_amdgcn_mfma_f32_16x16x32_bf16(qa[ks], kb[c], sf[c], 0, 0, 0);
        }

        const int rbase = row0 + w * 16;
        const bool full = (jt * 64 + 63 <= rbase);
        #pragma unroll
        for (int c = 0; c < 4; ++c) {
            const int jcol = jt * 64 + c * 16 + l15;
            #pragma unroll
            for (int reg = 0; reg < 4; ++reg) {
                const int rl = w * 16 + l4 * 4 + reg;
                float p = exp2f(fmaf(sf[c][reg], C2, nl2[reg]));
                if (!full && jcol > rbase + l4 * 4 + reg) p = 0.f;
                Ps[rl * 88 + c * 16 + l15] = f2b(p);
            }
        }
        if (jt + 1 < nt) {
            asm volatile("s_waitcnt vmcnt(2)" ::: "memory");   // V(jt) landed
        } else {
            asm volatile("s_waitcnt vmcnt(0)" ::: "memory");
        }
        __syncthreads();                   // C: Ps + Vt ready

        // coalesced NONTEMPORAL attn tile write from Ps
        #pragma unroll
        for (int i2 = 0; i2 < 4; ++i2) {
            const int idx = tid + i2 * 256;
            const int r = idx >> 4, c4 = (idx & 15) * 4;
            const ushort4 pb = *(const ushort4*)&Ps[r * 88 + c4];
            floatx4 pf;
            pf[0] = b2f(pb.x); pf[1] = b2f(pb.y); pf[2] = b2f(pb.z); pf[3] = b2f(pb.w);
            __builtin_nontemporal_store(
                pf, (floatx4*)(attnh + (size_t)(row0 + r) * S_LEN + jt * 64 + c4));
        }

        // PV MFMA
        #pragma unroll
        for (int ks = 0; ks < 2; ++ks) {
            const short8 pa = *(const short8*)&Ps[(w * 16 + l15) * 88 + ks * 32 + l4 * 8];
            #pragma unroll
            for (int c = 0; c < 4; ++c) {
                const int r = c * 16 + l15;
                const short8 vb = *(const short8*)&Vt[r * 64
                                                     + (((ks * 4 + l4) ^ (r & 7)) << 3)];
                o[c] = __builtin_amdgcn_mfma_f32_16x16x32_bf16(pa, vb, o[c], 0, 0, 0);
            }
        }
    }

    // context out (bf16, [B, S, H*64])
    const int b = bh >> 4, h = bh & 15;
    #pragma unroll
    for (int c = 0; c < 4; ++c)
        #pragma unroll
        for (int reg = 0; reg < 4; ++reg) {
            const int gr = row0 + w * 16 + l4 * 4 + reg;
            const int d = c * 16 + l15;
            ctx[((size_t)b * S_LEN + gr) * DMODEL + h * HD + d] = f2b(o[c][reg]);
        }

    // zero-fill strictly-above-diagonal tiles (nontemporal)
    const floatx4 z4 = {0.f, 0.f, 0.f, 0.f};
    for (int jt = nt; jt < S_LEN / 64; ++jt) {
        #pragma unroll
        for (int i = 0; i < 4; ++i) {
            const int idx = tid + i * 256;
            const int r = idx >> 4, off = (idx & 15) * 4;
            __builtin_nontemporal_store(
                z4, (floatx4*)(attnh + (size_t)(row0 + r) * S_LEN + jt * 64 + off));
        }
    }
}

// ---------------------------------------------------------------------------
extern "C" void kernel_launch(void* const* d_in, const int* in_sizes, int n_in,
                              void* d_out, int out_size, void* d_ws, size_t ws_size,
                              hipStream_t stream)
{
    const float* Q  = (const float*)d_in[0];
    const float* K  = (const float*)d_in[1];
    const float* V  = (const float*)d_in[2];
    const float* Wq = (const float*)d_in[4];
    const float* bq = (const float*)d_in[5];
    const float* Wk = (const float*)d_in[6];
    const float* bk = (const float*)d_in[7];
    const float* Wv = (const float*)d_in[8];
    const float* bv = (const float*)d_in[9];
    const float* Wo = (const float*)d_in[10];
    const float* bo = (const float*)d_in[11];

    float* out  = (float*)d_out;
    float* attn = out + (size_t)NBATCH * S_LEN * DMODEL;

    const size_t per = (size_t)NBATCH * S_LEN * DMODEL;
    const size_t wsz = (size_t)DMODEL * DMODEL;
    unsigned short* Xq  = (unsigned short*)d_ws;
    unsigned short* Xk  = Xq + per;
    unsigned short* Xv  = Xk + per;
    unsigned short* Wtq = Xv + per;
    unsigned short* Wtk = Wtq + wsz;
    unsigned short* Wtv = Wtk + wsz;
    unsigned short* Wto = Wtv + wsz;
    unsigned short* qhw = Wto + wsz;
    unsigned short* khw = qhw + per;
    unsigned short* vhw = khw + per;   // V transposed: [B,H,64,S]
    unsigned short* ctx = vhw + per;
    float* nl2g = (float*)(ctx + per); // [B*H, S]

    const int n4 = (int)(per / 4);
    convert_bf16<<<dim3((n4 + 255) / 256, 1, 3), 256, 0, stream>>>(
        Q, K, V, Xq, Xk, Xv, n4);
    transpose_w<<<dim3(16, 16, 4), 256, 0, stream>>>(Wq, Wk, Wv, Wo, Wtq, Wtk, Wtv, Wto);

    gemm_qkv<<<dim3(DMODEL / 128, (NBATCH * S_LEN) / 128, 3), 256, 0, stream>>>(
        Xq, Xk, Xv, Wtq, Wtk, Wtv, bq, bk, bv, qhw, khw, vhw);

    attn_stats<<<512, 256, 0, stream>>>(qhw, khw, nl2g);
    attn_write<<<1024, 256, 0, stream>>>(qhw, khw, vhw, nl2g, attn, ctx);

    gemm_out<<<dim3(DMODEL / 64, (NBATCH * S_LEN) / 128), 256, 0, stream>>>(
        ctx, Wto, bo, out);
}

// Round 15
// 231.491 us; speedup vs baseline: 1.1149x; 1.1149x over previous
//
#include <hip/hip_runtime.h>
#include <math.h>

#define S_LEN 2048
#define DMODEL 1024
#define NHEAD 16
#define HD 64
#define NBATCH 2

using short8  = __attribute__((ext_vector_type(8))) short;
using ushort8 = __attribute__((ext_vector_type(8))) unsigned short;
using floatx4 = __attribute__((ext_vector_type(4))) float;

__device__ __forceinline__ unsigned short f2b(float f) {
    unsigned int u = __float_as_uint(f);
    unsigned int r = (u + 0x7FFFu + ((u >> 16) & 1u)) >> 16;
    return (unsigned short)r;
}
__device__ __forceinline__ float b2f(unsigned short b) {
    return __uint_as_float(((unsigned int)b) << 16);
}

// async global->LDS, 16B per lane; LDS dest = wave-uniform base + lane*16
__device__ __forceinline__ void gll16(const void* g, void* l) {
    __builtin_amdgcn_global_load_lds(
        (const __attribute__((address_space(1))) unsigned int*)g,
        (__attribute__((address_space(3))) unsigned int*)l, 16, 0, 0);
}

// ---------------------------------------------------------------------------
// fp32 -> bf16 convert; z selects Q/K/V
// ---------------------------------------------------------------------------
__global__ __launch_bounds__(256)
void convert_bf16(const float* __restrict__ S0, const float* __restrict__ S1,
                  const float* __restrict__ S2,
                  unsigned short* __restrict__ D0, unsigned short* __restrict__ D1,
                  unsigned short* __restrict__ D2, int n4)
{
    const float* src = (blockIdx.z == 0) ? S0 : (blockIdx.z == 1) ? S1 : S2;
    unsigned short* dst = (blockIdx.z == 0) ? D0 : (blockIdx.z == 1) ? D1 : D2;
    int i = blockIdx.x * 256 + threadIdx.x;
    if (i < n4) {
        float4 v = ((const float4*)src)[i];
        ushort4 o;
        o.x = f2b(v.x); o.y = f2b(v.y); o.z = f2b(v.z); o.w = f2b(v.w);
        ((ushort4*)dst)[i] = o;
    }
}

// ---------------------------------------------------------------------------
__global__ __launch_bounds__(256)
void transpose_w(const float* __restrict__ W0, const float* __restrict__ W1,
                 const float* __restrict__ W2, const float* __restrict__ W3,
                 unsigned short* __restrict__ T0, unsigned short* __restrict__ T1,
                 unsigned short* __restrict__ T2, unsigned short* __restrict__ T3)
{
    __shared__ float t[64][65];
    const float* W; unsigned short* T;
    switch (blockIdx.z) {
        case 0: W = W0; T = T0; break;
        case 1: W = W1; T = T1; break;
        case 2: W = W2; T = T2; break;
        default: W = W3; T = T3; break;
    }
    const int tid = threadIdx.x;
    const int c0 = blockIdx.x * 64;
    const int r0 = blockIdx.y * 64;
    #pragma unroll
    for (int i = 0; i < 4; ++i) {
        int c = tid + i * 256;
        int r = c >> 4, off = (c & 15) * 4;
        float4 v = *(const float4*)(W + (size_t)(r0 + r) * DMODEL + c0 + off);
        t[r][off + 0] = v.x; t[r][off + 1] = v.y;
        t[r][off + 2] = v.z; t[r][off + 3] = v.w;
    }
    __syncthreads();
    #pragma unroll
    for (int i = 0; i < 4; ++i) {
        int c = tid + i * 256;
        int n = c >> 4, off = (c & 15) * 4;
        ushort4 o;
        o.x = f2b(t[off + 0][n]); o.y = f2b(t[off + 1][n]);
        o.z = f2b(t[off + 2][n]); o.w = f2b(t[off + 3][n]);
        *(ushort4*)(T + (size_t)(c0 + n) * DMODEL + r0 + off) = o;
    }
}

// ---------------------------------------------------------------------------
// QKV GEMM, tile 128x128, BK=64, global_load_lds staging with XOR swizzle.
// z==0/1 (Q/K): head-major [B,H,S,64]. z==2 (V): TRANSPOSED [B,H,64,S].
// ---------------------------------------------------------------------------
__global__ __launch_bounds__(256)
void gemm_qkv(const unsigned short* __restrict__ X0, const unsigned short* __restrict__ X1,
              const unsigned short* __restrict__ X2,
              const unsigned short* __restrict__ W0, const unsigned short* __restrict__ W1,
              const unsigned short* __restrict__ W2,
              const float* __restrict__ b0, const float* __restrict__ b1,
              const float* __restrict__ b2,
              unsigned short* __restrict__ o0, unsigned short* __restrict__ o1,
              unsigned short* __restrict__ o2)
{
    __shared__ unsigned short Xs[128 * 64];
    __shared__ unsigned short Ws[128 * 64];

    const unsigned short* X  = (blockIdx.z == 0) ? X0 : (blockIdx.z == 1) ? X1 : X2;
    const unsigned short* Wt = (blockIdx.z == 0) ? W0 : (blockIdx.z == 1) ? W1 : W2;
    const float* bias        = (blockIdx.z == 0) ? b0 : (blockIdx.z == 1) ? b1 : b2;
    unsigned short* outp     = (blockIdx.z == 0) ? o0 : (blockIdx.z == 1) ? o1 : o2;

    const int tid = threadIdx.x;
    const int lane = tid & 63, w = tid >> 6;
    const int l15 = lane & 15, l4 = lane >> 4;
    const int wr = w >> 1, wc = w & 1;
    const int row0 = blockIdx.y * 128;
    const int col0 = blockIdx.x * 128;

    const int srow = lane >> 3;
    const int sblk = (lane & 7) ^ srow;

    floatx4 acc[4][4] = {};

    for (int k0 = 0; k0 < DMODEL; k0 += 64) {
        __syncthreads();
        #pragma unroll
        for (int i = 0; i < 4; ++i)
            gll16(X + (size_t)(row0 + w * 32 + i * 8 + srow) * DMODEL + k0 + sblk * 8,
                  &Xs[(w * 32 + i * 8) * 64]);
        #pragma unroll
        for (int i = 0; i < 4; ++i)
            gll16(Wt + (size_t)(col0 + w * 32 + i * 8 + srow) * DMODEL + k0 + sblk * 8,
                  &Ws[(w * 32 + i * 8) * 64]);
        asm volatile("s_waitcnt vmcnt(0)" ::: "memory");
        __syncthreads();

        #pragma unroll
        for (int ks = 0; ks < 2; ++ks) {
            short8 a[4], b[4];
            #pragma unroll
            for (int m = 0; m < 4; ++m) {
                const int r = wr * 64 + m * 16 + l15;
                a[m] = *(const short8*)&Xs[r * 64 + (((ks * 4 + l4) ^ (r & 7)) << 3)];
            }
            #pragma unroll
            for (int n = 0; n < 4; ++n) {
                const int r = wc * 64 + n * 16 + l15;
                b[n] = *(const short8*)&Ws[r * 64 + (((ks * 4 + l4) ^ (r & 7)) << 3)];
            }
            #pragma unroll
            for (int m = 0; m < 4; ++m)
                #pragma unroll
                for (int n = 0; n < 4; ++n)
                    acc[m][n] = __builtin_amdgcn_mfma_f32_16x16x32_bf16(
                        a[m], b[n], acc[m][n], 0, 0, 0);
        }
    }

    float bl[4];
    #pragma unroll
    for (int n = 0; n < 4; ++n)
        bl[n] = bias[col0 + wc * 64 + n * 16 + l15];

    if (blockIdx.z != 2) {
        #pragma unroll
        for (int m = 0; m < 4; ++m)
            #pragma unroll
            for (int n = 0; n < 4; ++n) {
                const int gc = col0 + wc * 64 + n * 16 + l15;
                const int h = gc >> 6, d = gc & 63;
                #pragma unroll
                for (int reg = 0; reg < 4; ++reg) {
                    const int gr = row0 + wr * 64 + m * 16 + l4 * 4 + reg;
                    const int bb = gr >> 11, s = gr & 2047;
                    outp[(((size_t)bb * NHEAD + h) * S_LEN + s) * HD + d] =
                        f2b(acc[m][n][reg] + bl[n]);
                }
            }
    } else {
        #pragma unroll
        for (int m = 0; m < 4; ++m)
            #pragma unroll
            for (int n = 0; n < 4; ++n) {
                const int gc = col0 + wc * 64 + n * 16 + l15;
                const int h = gc >> 6, d = gc & 63;
                const int s0 = row0 + wr * 64 + m * 16 + l4 * 4;
                const int bb = s0 >> 11, sr = s0 & 2047;
                ushort4 pk;
                pk.x = f2b(acc[m][n][0] + bl[n]);
                pk.y = f2b(acc[m][n][1] + bl[n]);
                pk.z = f2b(acc[m][n][2] + bl[n]);
                pk.w = f2b(acc[m][n][3] + bl[n]);
                *(ushort4*)(outp + (((size_t)bb * NHEAD + h) * HD + d) * S_LEN + sr) = pk;
            }
    }
}

// ---------------------------------------------------------------------------
// Output projection GEMM, tile 128x64 -> grid (16,32)=512 wg = 2 blocks/CU.
// ---------------------------------------------------------------------------
__global__ __launch_bounds__(256)
void gemm_out(const unsigned short* __restrict__ X, const unsigned short* __restrict__ Wt,
              const float* __restrict__ bias, float* __restrict__ out)
{
    __shared__ unsigned short Xs[128 * 64];
    __shared__ unsigned short Ws[64 * 64];

    const int tid = threadIdx.x;
    const int lane = tid & 63, w = tid >> 6;
    const int l15 = lane & 15, l4 = lane >> 4;
    const int wr = w >> 1, wc = w & 1;
    const int row0 = blockIdx.y * 128;
    const int col0 = blockIdx.x * 64;

    const int srow = lane >> 3;
    const int sblk = (lane & 7) ^ srow;

    floatx4 acc[4][2] = {};

    for (int k0 = 0; k0 < DMODEL; k0 += 64) {
        __syncthreads();
        #pragma unroll
        for (int i = 0; i < 4; ++i)
            gll16(X + (size_t)(row0 + w * 32 + i * 8 + srow) * DMODEL + k0 + sblk * 8,
                  &Xs[(w * 32 + i * 8) * 64]);
        #pragma unroll
        for (int i = 0; i < 2; ++i)
            gll16(Wt + (size_t)(col0 + w * 16 + i * 8 + srow) * DMODEL + k0 + sblk * 8,
                  &Ws[(w * 16 + i * 8) * 64]);
        asm volatile("s_waitcnt vmcnt(0)" ::: "memory");
        __syncthreads();

        #pragma unroll
        for (int ks = 0; ks < 2; ++ks) {
            short8 a[4], b[2];
            #pragma unroll
            for (int m = 0; m < 4; ++m) {
                const int r = wr * 64 + m * 16 + l15;
                a[m] = *(const short8*)&Xs[r * 64 + (((ks * 4 + l4) ^ (r & 7)) << 3)];
            }
            #pragma unroll
            for (int n = 0; n < 2; ++n) {
                const int r = wc * 32 + n * 16 + l15;
                b[n] = *(const short8*)&Ws[r * 64 + (((ks * 4 + l4) ^ (r & 7)) << 3)];
            }
            #pragma unroll
            for (int m = 0; m < 4; ++m)
                #pragma unroll
                for (int n = 0; n < 2; ++n)
                    acc[m][n] = __builtin_amdgcn_mfma_f32_16x16x32_bf16(
                        a[m], b[n], acc[m][n], 0, 0, 0);
        }
    }

    float bl[2];
    #pragma unroll
    for (int n = 0; n < 2; ++n)
        bl[n] = bias[col0 + wc * 32 + n * 16 + l15];

    #pragma unroll
    for (int m = 0; m < 4; ++m)
        #pragma unroll
        for (int n = 0; n < 2; ++n) {
            const int gc = col0 + wc * 32 + n * 16 + l15;
            #pragma unroll
            for (int reg = 0; reg < 4; ++reg) {
                const int gr = row0 + wr * 64 + m * 16 + l4 * 4 + reg;
                out[(size_t)gr * DMODEL + gc] = acc[m][n][reg] + bl[n];
            }
        }
}

// ---------------------------------------------------------------------------
// Attention (R12 structure restored). ONLY change vs R12: s_setprio(1)/(0)
// around the QK^T and PV MFMA clusters — isolated T5 probe (4 independent
// blocks/CU at different causal lengths = wave role diversity).
// ---------------------------------------------------------------------------
__global__ __launch_bounds__(256)
void attn_mfma(const unsigned short* __restrict__ qg, const unsigned short* __restrict__ kg,
               const unsigned short* __restrict__ vtg, float* __restrict__ attn,
               unsigned short* __restrict__ ctx)
{
    __shared__ unsigned short Ks[2 * 64 * 64];
    __shared__ unsigned short Vt[64 * 64];
    __shared__ unsigned short Ps[64 * 88];

    const int tid = threadIdx.x;
    const int lane = tid & 63, w = tid >> 6;
    const int l15 = lane & 15, l4 = lane >> 4;

    const int i0 = blockIdx.x;
    const int local = i0 >> 3;
    const int bh = (i0 & 7) * 4 + (local & 3);
    const int qx = local >> 2;
    const int qb = (bh & 1) ? (31 - qx) : qx;
    const int row0 = qb * 64;

    const int srow = lane >> 3;
    const int sblk = (lane & 7) ^ srow;

    const float C2 = 0.18033688011112042f;   // 0.125 * log2(e)

    const unsigned short* qh = qg + (size_t)bh * S_LEN * HD;
    const unsigned short* kh = kg + (size_t)bh * S_LEN * HD;
    const unsigned short* vth = vtg + (size_t)bh * HD * S_LEN;   // [d][s]
    float* attnh = attn + (size_t)bh * S_LEN * S_LEN;

    short8 qa[2];
    #pragma unroll
    for (int ks = 0; ks < 2; ++ks)
        qa[ks] = *(const short8*)(qh + (size_t)(row0 + w * 16 + l15) * HD + ks * 32 + l4 * 8);

    const int nt = qb + 1;

    // ---- pass 1: row sums; K dbuf + counted vmcnt ----
    #pragma unroll
    for (int i = 0; i < 2; ++i)
        gll16(kh + (size_t)(w * 16 + i * 8 + srow) * HD + sblk * 8,
              &Ks[(w * 16 + i * 8) * 64]);

    float lsum[4] = {};
    for (int jt = 0; jt < nt; ++jt) {
        const int cur = jt & 1;
        __syncthreads();
        if (jt + 1 < nt) {
            #pragma unroll
            for (int i = 0; i < 2; ++i)
                gll16(kh + (size_t)((jt + 1) * 64 + w * 16 + i * 8 + srow) * HD + sblk * 8,
                      &Ks[(cur ^ 1) * 4096 + (w * 16 + i * 8) * 64]);
            asm volatile("s_waitcnt vmcnt(2)" ::: "memory");
        } else {
            asm volatile("s_waitcnt vmcnt(0)" ::: "memory");
        }
        __syncthreads();

        floatx4 sf[4] = {};
        __builtin_amdgcn_s_setprio(1);
        #pragma unroll
        for (int ks = 0; ks < 2; ++ks) {
            short8 kb[4];
            #pragma unroll
            for (int c = 0; c < 4; ++c) {
                const int r = c * 16 + l15;
                kb[c] = *(const short8*)&Ks[cur * 4096 + r * 64
                                            + (((ks * 4 + l4) ^ (r & 7)) << 3)];
            }
            #pragma unroll
            for (int c = 0; c < 4; ++c)
                sf[c] = __builtin_amdgcn_mfma_f32_16x16x32_bf16(qa[ks], kb[c], sf[c], 0, 0, 0);
        }
        __builtin_amdgcn_s_setprio(0);

        const int rbase = row0 + w * 16;
        if (jt * 64 + 63 <= rbase) {
            #pragma unroll
            for (int c = 0; c < 4; ++c)
                #pragma unroll
                for (int reg = 0; reg < 4; ++reg)
                    lsum[reg] += exp2f(sf[c][reg] * C2);
        } else {
            #pragma unroll
            for (int c = 0; c < 4; ++c) {
                const int jcol = jt * 64 + c * 16 + l15;
                #pragma unroll
                for (int reg = 0; reg < 4; ++reg) {
                    const int grow = rbase + l4 * 4 + reg;
                    lsum[reg] += (jcol <= grow) ? exp2f(sf[c][reg] * C2) : 0.f;
                }
            }
        }
    }

    float nl2[4];
    #pragma unroll
    for (int reg = 0; reg < 4; ++reg) {
        float s = lsum[reg];
        #pragma unroll
        for (int off = 1; off < 16; off <<= 1)
            s += __shfl_xor(s, off);
        nl2[reg] = -__log2f(s);
    }

    // ---- pass 2: P write + PV; K and V both gll16-staged ----
    floatx4 o[4] = {};

    __syncthreads();                      // pass-1 Ks reads done before restage
    #pragma unroll
    for (int i = 0; i < 2; ++i)
        gll16(kh + (size_t)(w * 16 + i * 8 + srow) * HD + sblk * 8,
              &Ks[(w * 16 + i * 8) * 64]);

    for (int jt = 0; jt < nt; ++jt) {
        const int buf = jt & 1;
        asm volatile("s_waitcnt vmcnt(0)" ::: "memory");   // K(jt) landed
        __syncthreads();                   // B: all PV(jt-1) done; K(jt) visible

        // stage V(jt) (FIFO-older than K(jt+1))
        #pragma unroll
        for (int i = 0; i < 2; ++i)
            gll16(vth + (size_t)(w * 16 + i * 8 + srow) * S_LEN + jt * 64 + sblk * 8,
                  &Vt[(w * 16 + i * 8) * 64]);
        if (jt + 1 < nt) {
            #pragma unroll
            for (int i = 0; i < 2; ++i)
                gll16(kh + (size_t)((jt + 1) * 64 + w * 16 + i * 8 + srow) * HD + sblk * 8,
                      &Ks[(buf ^ 1) * 4096 + (w * 16 + i * 8) * 64]);
        }

        floatx4 sf[4] = {};
        __builtin_amdgcn_s_setprio(1);
        #pragma unroll
        for (int ks = 0; ks < 2; ++ks) {
            short8 kb[4];
            #pragma unroll
            for (int c = 0; c < 4; ++c) {
                const int r = c * 16 + l15;
                kb[c] = *(const short8*)&Ks[buf * 4096 + r * 64
                                            + (((ks * 4 + l4) ^ (r & 7)) << 3)];
            }
            #pragma unroll
            for (int c = 0; c < 4; ++c)
                sf[c] = __builtin_amdgcn_mfma_f32_16x16x32_bf16(qa[ks], kb[c], sf[c], 0, 0, 0);
        }
        __builtin_amdgcn_s_setprio(0);

        const int rbase = row0 + w * 16;
        const bool full = (jt * 64 + 63 <= rbase);
        #pragma unroll
        for (int c = 0; c < 4; ++c) {
            const int jcol = jt * 64 + c * 16 + l15;
            #pragma unroll
            for (int reg = 0; reg < 4; ++reg) {
                const int rl = w * 16 + l4 * 4 + reg;
                float p = exp2f(fmaf(sf[c][reg], C2, nl2[reg]));
                if (!full && jcol > rbase + l4 * 4 + reg) p = 0.f;
                Ps[rl * 88 + c * 16 + l15] = f2b(p);
            }
        }
        if (jt + 1 < nt) {
            asm volatile("s_waitcnt vmcnt(2)" ::: "memory");   // V(jt) landed
        } else {
            asm volatile("s_waitcnt vmcnt(0)" ::: "memory");
        }
        __syncthreads();                   // C: Ps + Vt ready

        // coalesced NONTEMPORAL attn tile write from Ps
        #pragma unroll
        for (int i2 = 0; i2 < 4; ++i2) {
            const int idx = tid + i2 * 256;
            const int r = idx >> 4, c4 = (idx & 15) * 4;
            const ushort4 pb = *(const ushort4*)&Ps[r * 88 + c4];
            floatx4 pf;
            pf[0] = b2f(pb.x); pf[1] = b2f(pb.y); pf[2] = b2f(pb.z); pf[3] = b2f(pb.w);
            __builtin_nontemporal_store(
                pf, (floatx4*)(attnh + (size_t)(row0 + r) * S_LEN + jt * 64 + c4));
        }

        // PV MFMA
        __builtin_amdgcn_s_setprio(1);
        #pragma unroll
        for (int ks = 0; ks < 2; ++ks) {
            const short8 pa = *(const short8*)&Ps[(w * 16 + l15) * 88 + ks * 32 + l4 * 8];
            #pragma unroll
            for (int c = 0; c < 4; ++c) {
                const int r = c * 16 + l15;
                const short8 vb = *(const short8*)&Vt[r * 64
                                                     + (((ks * 4 + l4) ^ (r & 7)) << 3)];
                o[c] = __builtin_amdgcn_mfma_f32_16x16x32_bf16(pa, vb, o[c], 0, 0, 0);
            }
        }
        __builtin_amdgcn_s_setprio(0);
    }

    // context out (bf16, [B, S, H*64])
    const int b = bh >> 4, h = bh & 15;
    #pragma unroll
    for (int c = 0; c < 4; ++c)
        #pragma unroll
        for (int reg = 0; reg < 4; ++reg) {
            const int gr = row0 + w * 16 + l4 * 4 + reg;
            const int d = c * 16 + l15;
            ctx[((size_t)b * S_LEN + gr) * DMODEL + h * HD + d] = f2b(o[c][reg]);
        }

    // zero-fill strictly-above-diagonal tiles (nontemporal)
    const floatx4 z4 = {0.f, 0.f, 0.f, 0.f};
    for (int jt = nt; jt < S_LEN / 64; ++jt) {
        #pragma unroll
        for (int i = 0; i < 4; ++i) {
            const int idx = tid + i * 256;
            const int r = idx >> 4, off = (idx & 15) * 4;
            __builtin_nontemporal_store(
                z4, (floatx4*)(attnh + (size_t)(row0 + r) * S_LEN + jt * 64 + off));
        }
    }
}

// ---------------------------------------------------------------------------
extern "C" void kernel_launch(void* const* d_in, const int* in_sizes, int n_in,
                              void* d_out, int out_size, void* d_ws, size_t ws_size,
                              hipStream_t stream)
{
    const float* Q  = (const float*)d_in[0];
    const float* K  = (const float*)d_in[1];
    const float* V  = (const float*)d_in[2];
    const float* Wq = (const float*)d_in[4];
    const float* bq = (const float*)d_in[5];
    const float* Wk = (const float*)d_in[6];
    const float* bk = (const float*)d_in[7];
    const float* Wv = (const float*)d_in[8];
    const float* bv = (const float*)d_in[9];
    const float* Wo = (const float*)d_in[10];
    const float* bo = (const float*)d_in[11];

    float* out  = (float*)d_out;
    float* attn = out + (size_t)NBATCH * S_LEN * DMODEL;

    const size_t per = (size_t)NBATCH * S_LEN * DMODEL;
    const size_t wsz = (size_t)DMODEL * DMODEL;
    unsigned short* Xq  = (unsigned short*)d_ws;
    unsigned short* Xk  = Xq + per;
    unsigned short* Xv  = Xk + per;
    unsigned short* Wtq = Xv + per;
    unsigned short* Wtk = Wtq + wsz;
    unsigned short* Wtv = Wtk + wsz;
    unsigned short* Wto = Wtv + wsz;
    unsigned short* qhw = Wto + wsz;
    unsigned short* khw = qhw + per;
    unsigned short* vhw = khw + per;   // V transposed: [B,H,64,S]
    unsigned short* ctx = vhw + per;

    const int n4 = (int)(per / 4);
    convert_bf16<<<dim3((n4 + 255) / 256, 1, 3), 256, 0, stream>>>(
        Q, K, V, Xq, Xk, Xv, n4);
    transpose_w<<<dim3(16, 16, 4), 256, 0, stream>>>(Wq, Wk, Wv, Wo, Wtq, Wtk, Wtv, Wto);

    gemm_qkv<<<dim3(DMODEL / 128, (NBATCH * S_LEN) / 128, 3), 256, 0, stream>>>(
        Xq, Xk, Xv, Wtq, Wtk, Wtv, bq, bk, bv, qhw, khw, vhw);

    attn_mfma<<<1024, 256, 0, stream>>>(qhw, khw, vhw, attn, ctx);

    gemm_out<<<dim3(DMODEL / 64, (NBATCH * S_LEN) / 128), 256, 0, stream>>>(
        ctx, Wto, bo, out);
}

// Round 16
// 229.348 us; speedup vs baseline: 1.1253x; 1.0093x over previous
//
#include <hip/hip_runtime.h>
#include <math.h>

#define S_LEN 2048
#define DMODEL 1024
#define NHEAD 16
#define HD 64
#define NBATCH 2

using short8  = __attribute__((ext_vector_type(8))) short;
using ushort8 = __attribute__((ext_vector_type(8))) unsigned short;
using floatx4 = __attribute__((ext_vector_type(4))) float;

__device__ __forceinline__ unsigned short f2b(float f) {
    unsigned int u = __float_as_uint(f);
    unsigned int r = (u + 0x7FFFu + ((u >> 16) & 1u)) >> 16;
    return (unsigned short)r;
}
__device__ __forceinline__ float b2f(unsigned short b) {
    return __uint_as_float(((unsigned int)b) << 16);
}

// async global->LDS, 16B per lane; LDS dest = wave-uniform base + lane*16
__device__ __forceinline__ void gll16(const void* g, void* l) {
    __builtin_amdgcn_global_load_lds(
        (const __attribute__((address_space(1))) unsigned int*)g,
        (__attribute__((address_space(3))) unsigned int*)l, 16, 0, 0);
}

// ---------------------------------------------------------------------------
// fp32 -> bf16 convert; z selects Q/K/V
// ---------------------------------------------------------------------------
__global__ __launch_bounds__(256)
void convert_bf16(const float* __restrict__ S0, const float* __restrict__ S1,
                  const float* __restrict__ S2,
                  unsigned short* __restrict__ D0, unsigned short* __restrict__ D1,
                  unsigned short* __restrict__ D2, int n4)
{
    const float* src = (blockIdx.z == 0) ? S0 : (blockIdx.z == 1) ? S1 : S2;
    unsigned short* dst = (blockIdx.z == 0) ? D0 : (blockIdx.z == 1) ? D1 : D2;
    int i = blockIdx.x * 256 + threadIdx.x;
    if (i < n4) {
        float4 v = ((const float4*)src)[i];
        ushort4 o;
        o.x = f2b(v.x); o.y = f2b(v.y); o.z = f2b(v.z); o.w = f2b(v.w);
        ((ushort4*)dst)[i] = o;
    }
}

// ---------------------------------------------------------------------------
__global__ __launch_bounds__(256)
void transpose_w(const float* __restrict__ W0, const float* __restrict__ W1,
                 const float* __restrict__ W2, const float* __restrict__ W3,
                 unsigned short* __restrict__ T0, unsigned short* __restrict__ T1,
                 unsigned short* __restrict__ T2, unsigned short* __restrict__ T3)
{
    __shared__ float t[64][65];
    const float* W; unsigned short* T;
    switch (blockIdx.z) {
        case 0: W = W0; T = T0; break;
        case 1: W = W1; T = T1; break;
        case 2: W = W2; T = T2; break;
        default: W = W3; T = T3; break;
    }
    const int tid = threadIdx.x;
    const int c0 = blockIdx.x * 64;
    const int r0 = blockIdx.y * 64;
    #pragma unroll
    for (int i = 0; i < 4; ++i) {
        int c = tid + i * 256;
        int r = c >> 4, off = (c & 15) * 4;
        float4 v = *(const float4*)(W + (size_t)(r0 + r) * DMODEL + c0 + off);
        t[r][off + 0] = v.x; t[r][off + 1] = v.y;
        t[r][off + 2] = v.z; t[r][off + 3] = v.w;
    }
    __syncthreads();
    #pragma unroll
    for (int i = 0; i < 4; ++i) {
        int c = tid + i * 256;
        int n = c >> 4, off = (c & 15) * 4;
        ushort4 o;
        o.x = f2b(t[off + 0][n]); o.y = f2b(t[off + 1][n]);
        o.z = f2b(t[off + 2][n]); o.w = f2b(t[off + 3][n]);
        *(ushort4*)(T + (size_t)(c0 + n) * DMODEL + r0 + off) = o;
    }
}

// ---------------------------------------------------------------------------
// QKV GEMM, tile 128x128, BK=64, global_load_lds staging with XOR swizzle.
// z==0/1 (Q/K): head-major [B,H,S,64]. z==2 (V): TRANSPOSED [B,H,64,S].
// ---------------------------------------------------------------------------
__global__ __launch_bounds__(256)
void gemm_qkv(const unsigned short* __restrict__ X0, const unsigned short* __restrict__ X1,
              const unsigned short* __restrict__ X2,
              const unsigned short* __restrict__ W0, const unsigned short* __restrict__ W1,
              const unsigned short* __restrict__ W2,
              const float* __restrict__ b0, const float* __restrict__ b1,
              const float* __restrict__ b2,
              unsigned short* __restrict__ o0, unsigned short* __restrict__ o1,
              unsigned short* __restrict__ o2)
{
    __shared__ unsigned short Xs[128 * 64];
    __shared__ unsigned short Ws[128 * 64];

    const unsigned short* X  = (blockIdx.z == 0) ? X0 : (blockIdx.z == 1) ? X1 : X2;
    const unsigned short* Wt = (blockIdx.z == 0) ? W0 : (blockIdx.z == 1) ? W1 : W2;
    const float* bias        = (blockIdx.z == 0) ? b0 : (blockIdx.z == 1) ? b1 : b2;
    unsigned short* outp     = (blockIdx.z == 0) ? o0 : (blockIdx.z == 1) ? o1 : o2;

    const int tid = threadIdx.x;
    const int lane = tid & 63, w = tid >> 6;
    const int l15 = lane & 15, l4 = lane >> 4;
    const int wr = w >> 1, wc = w & 1;
    const int row0 = blockIdx.y * 128;
    const int col0 = blockIdx.x * 128;

    const int srow = lane >> 3;
    const int sblk = (lane & 7) ^ srow;

    floatx4 acc[4][4] = {};

    for (int k0 = 0; k0 < DMODEL; k0 += 64) {
        __syncthreads();
        #pragma unroll
        for (int i = 0; i < 4; ++i)
            gll16(X + (size_t)(row0 + w * 32 + i * 8 + srow) * DMODEL + k0 + sblk * 8,
                  &Xs[(w * 32 + i * 8) * 64]);
        #pragma unroll
        for (int i = 0; i < 4; ++i)
            gll16(Wt + (size_t)(col0 + w * 32 + i * 8 + srow) * DMODEL + k0 + sblk * 8,
                  &Ws[(w * 32 + i * 8) * 64]);
        asm volatile("s_waitcnt vmcnt(0)" ::: "memory");
        __syncthreads();

        #pragma unroll
        for (int ks = 0; ks < 2; ++ks) {
            short8 a[4], b[4];
            #pragma unroll
            for (int m = 0; m < 4; ++m) {
                const int r = wr * 64 + m * 16 + l15;
                a[m] = *(const short8*)&Xs[r * 64 + (((ks * 4 + l4) ^ (r & 7)) << 3)];
            }
            #pragma unroll
            for (int n = 0; n < 4; ++n) {
                const int r = wc * 64 + n * 16 + l15;
                b[n] = *(const short8*)&Ws[r * 64 + (((ks * 4 + l4) ^ (r & 7)) << 3)];
            }
            #pragma unroll
            for (int m = 0; m < 4; ++m)
                #pragma unroll
                for (int n = 0; n < 4; ++n)
                    acc[m][n] = __builtin_amdgcn_mfma_f32_16x16x32_bf16(
                        a[m], b[n], acc[m][n], 0, 0, 0);
        }
    }

    float bl[4];
    #pragma unroll
    for (int n = 0; n < 4; ++n)
        bl[n] = bias[col0 + wc * 64 + n * 16 + l15];

    if (blockIdx.z != 2) {
        #pragma unroll
        for (int m = 0; m < 4; ++m)
            #pragma unroll
            for (int n = 0; n < 4; ++n) {
                const int gc = col0 + wc * 64 + n * 16 + l15;
                const int h = gc >> 6, d = gc & 63;
                #pragma unroll
                for (int reg = 0; reg < 4; ++reg) {
                    const int gr = row0 + wr * 64 + m * 16 + l4 * 4 + reg;
                    const int bb = gr >> 11, s = gr & 2047;
                    outp[(((size_t)bb * NHEAD + h) * S_LEN + s) * HD + d] =
                        f2b(acc[m][n][reg] + bl[n]);
                }
            }
    } else {
        #pragma unroll
        for (int m = 0; m < 4; ++m)
            #pragma unroll
            for (int n = 0; n < 4; ++n) {
                const int gc = col0 + wc * 64 + n * 16 + l15;
                const int h = gc >> 6, d = gc & 63;
                const int s0 = row0 + wr * 64 + m * 16 + l4 * 4;
                const int bb = s0 >> 11, sr = s0 & 2047;
                ushort4 pk;
                pk.x = f2b(acc[m][n][0] + bl[n]);
                pk.y = f2b(acc[m][n][1] + bl[n]);
                pk.z = f2b(acc[m][n][2] + bl[n]);
                pk.w = f2b(acc[m][n][3] + bl[n]);
                *(ushort4*)(outp + (((size_t)bb * NHEAD + h) * HD + d) * S_LEN + sr) = pk;
            }
    }
}

// ---------------------------------------------------------------------------
// Output projection GEMM, tile 128x64 -> grid (16,32)=512 wg = 2 blocks/CU.
// ---------------------------------------------------------------------------
__global__ __launch_bounds__(256)
void gemm_out(const unsigned short* __restrict__ X, const unsigned short* __restrict__ Wt,
              const float* __restrict__ bias, float* __restrict__ out)
{
    __shared__ unsigned short Xs[128 * 64];
    __shared__ unsigned short Ws[64 * 64];

    const int tid = threadIdx.x;
    const int lane = tid & 63, w = tid >> 6;
    const int l15 = lane & 15, l4 = lane >> 4;
    const int wr = w >> 1, wc = w & 1;
    const int row0 = blockIdx.y * 128;
    const int col0 = blockIdx.x * 64;

    const int srow = lane >> 3;
    const int sblk = (lane & 7) ^ srow;

    floatx4 acc[4][2] = {};

    for (int k0 = 0; k0 < DMODEL; k0 += 64) {
        __syncthreads();
        #pragma unroll
        for (int i = 0; i < 4; ++i)
            gll16(X + (size_t)(row0 + w * 32 + i * 8 + srow) * DMODEL + k0 + sblk * 8,
                  &Xs[(w * 32 + i * 8) * 64]);
        #pragma unroll
        for (int i = 0; i < 2; ++i)
            gll16(Wt + (size_t)(col0 + w * 16 + i * 8 + srow) * DMODEL + k0 + sblk * 8,
                  &Ws[(w * 16 + i * 8) * 64]);
        asm volatile("s_waitcnt vmcnt(0)" ::: "memory");
        __syncthreads();

        #pragma unroll
        for (int ks = 0; ks < 2; ++ks) {
            short8 a[4], b[2];
            #pragma unroll
            for (int m = 0; m < 4; ++m) {
                const int r = wr * 64 + m * 16 + l15;
                a[m] = *(const short8*)&Xs[r * 64 + (((ks * 4 + l4) ^ (r & 7)) << 3)];
            }
            #pragma unroll
            for (int n = 0; n < 2; ++n) {
                const int r = wc * 32 + n * 16 + l15;
                b[n] = *(const short8*)&Ws[r * 64 + (((ks * 4 + l4) ^ (r & 7)) << 3)];
            }
            #pragma unroll
            for (int m = 0; m < 4; ++m)
                #pragma unroll
                for (int n = 0; n < 2; ++n)
                    acc[m][n] = __builtin_amdgcn_mfma_f32_16x16x32_bf16(
                        a[m], b[n], acc[m][n], 0, 0, 0);
        }
    }

    float bl[2];
    #pragma unroll
    for (int n = 0; n < 2; ++n)
        bl[n] = bias[col0 + wc * 32 + n * 16 + l15];

    #pragma unroll
    for (int m = 0; m < 4; ++m)
        #pragma unroll
        for (int n = 0; n < 2; ++n) {
            const int gc = col0 + wc * 32 + n * 16 + l15;
            #pragma unroll
            for (int reg = 0; reg < 4; ++reg) {
                const int gr = row0 + wr * 64 + m * 16 + l4 * 4 + reg;
                out[(size_t)gr * DMODEL + gc] = acc[m][n][reg] + bl[n];
            }
        }
}

// ---------------------------------------------------------------------------
// Attention (R12 structure + T3/T4 raw-barrier discipline):
// __syncthreads (which drains vmcnt(0), forcing NT-store completion onto the
// critical path) replaced by raw s_barrier with exact counted waits; NT
// stores moved AFTER PV so they are the youngest VMEM ops and are never
// force-drained in-loop (stores from tile jt-1 are >1 iteration old when
// vmcnt(2) passes them).
// Pass-2 ledger (steady state): entry [K(jt)2, St(jt-1)4] -> vmcnt(4)
// retires K; post-Ps [St4,V2,K2] -> vmcnt(2)+lgkmcnt(0) retires V.
// ---------------------------------------------------------------------------
__global__ __launch_bounds__(256)
void attn_mfma(const unsigned short* __restrict__ qg, const unsigned short* __restrict__ kg,
               const unsigned short* __restrict__ vtg, float* __restrict__ attn,
               unsigned short* __restrict__ ctx)
{
    __shared__ unsigned short Ks[2 * 64 * 64];
    __shared__ unsigned short Vt[64 * 64];
    __shared__ unsigned short Ps[64 * 88];

    const int tid = threadIdx.x;
    const int lane = tid & 63, w = tid >> 6;
    const int l15 = lane & 15, l4 = lane >> 4;

    const int i0 = blockIdx.x;
    const int local = i0 >> 3;
    const int bh = (i0 & 7) * 4 + (local & 3);
    const int qx = local >> 2;
    const int qb = (bh & 1) ? (31 - qx) : qx;
    const int row0 = qb * 64;

    const int srow = lane >> 3;
    const int sblk = (lane & 7) ^ srow;

    const float C2 = 0.18033688011112042f;   // 0.125 * log2(e)

    const unsigned short* qh = qg + (size_t)bh * S_LEN * HD;
    const unsigned short* kh = kg + (size_t)bh * S_LEN * HD;
    const unsigned short* vth = vtg + (size_t)bh * HD * S_LEN;   // [d][s]
    float* attnh = attn + (size_t)bh * S_LEN * S_LEN;

    short8 qa[2];
    #pragma unroll
    for (int ks = 0; ks < 2; ++ks)
        qa[ks] = *(const short8*)(qh + (size_t)(row0 + w * 16 + l15) * HD + ks * 32 + l4 * 8);

    const int nt = qb + 1;

    // ---- pass 1: row sums; K dbuf, raw barriers + counted vmcnt ----
    #pragma unroll
    for (int i = 0; i < 2; ++i)
        gll16(kh + (size_t)(w * 16 + i * 8 + srow) * HD + sblk * 8,
              &Ks[(w * 16 + i * 8) * 64]);

    float lsum[4] = {};
    for (int jt = 0; jt < nt; ++jt) {
        const int cur = jt & 1;
        __builtin_amdgcn_s_barrier();      // A: prev reads of Ks[cur^1] consumed
        if (jt + 1 < nt) {
            #pragma unroll
            for (int i = 0; i < 2; ++i)
                gll16(kh + (size_t)((jt + 1) * 64 + w * 16 + i * 8 + srow) * HD + sblk * 8,
                      &Ks[(cur ^ 1) * 4096 + (w * 16 + i * 8) * 64]);
            asm volatile("s_waitcnt vmcnt(2)" ::: "memory");   // K(jt) landed
        } else {
            asm volatile("s_waitcnt vmcnt(0)" ::: "memory");
        }
        __builtin_amdgcn_s_barrier();      // B: K(jt) visible to all waves

        floatx4 sf[4] = {};
        #pragma unroll
        for (int ks = 0; ks < 2; ++ks) {
            short8 kb[4];
            #pragma unroll
            for (int c = 0; c < 4; ++c) {
                const int r = c * 16 + l15;
                kb[c] = *(const short8*)&Ks[cur * 4096 + r * 64
                                            + (((ks * 4 + l4) ^ (r & 7)) << 3)];
            }
            #pragma unroll
            for (int c = 0; c < 4; ++c)
                sf[c] = __builtin_amdgcn_mfma_f32_16x16x32_bf16(qa[ks], kb[c], sf[c], 0, 0, 0);
        }

        const int rbase = row0 + w * 16;
        if (jt * 64 + 63 <= rbase) {
            #pragma unroll
            for (int c = 0; c < 4; ++c)
                #pragma unroll
                for (int reg = 0; reg < 4; ++reg)
                    lsum[reg] += exp2f(sf[c][reg] * C2);
        } else {
            #pragma unroll
            for (int c = 0; c < 4; ++c) {
                const int jcol = jt * 64 + c * 16 + l15;
                #pragma unroll
                for (int reg = 0; reg < 4; ++reg) {
                    const int grow = rbase + l4 * 4 + reg;
                    lsum[reg] += (jcol <= grow) ? exp2f(sf[c][reg] * C2) : 0.f;
                }
            }
        }
    }

    float nl2[4];
    #pragma unroll
    for (int reg = 0; reg < 4; ++reg) {
        float s = lsum[reg];
        #pragma unroll
        for (int off = 1; off < 16; off <<= 1)
            s += __shfl_xor(s, off);
        nl2[reg] = -__log2f(s);
    }

    // ---- transition: full drain once, then prologue K(0) ----
    asm volatile("s_waitcnt vmcnt(0) lgkmcnt(0)" ::: "memory");
    __builtin_amdgcn_s_barrier();
    #pragma unroll
    for (int i = 0; i < 2; ++i)
        gll16(kh + (size_t)(w * 16 + i * 8 + srow) * HD + sblk * 8,
              &Ks[(w * 16 + i * 8) * 64]);

    // ---- pass 2: QK^T + P + PV; raw barriers, stores last (never drained) --
    floatx4 o[4] = {};
    for (int jt = 0; jt < nt; ++jt) {
        const int buf = jt & 1;
        if (jt == 0) {
            asm volatile("s_waitcnt vmcnt(0)" ::: "memory");   // K(0) landed
        } else {
            asm volatile("s_waitcnt vmcnt(4)" ::: "memory");   // K(jt) landed; St(jt-1) fly
        }
        __builtin_amdgcn_s_barrier();      // B: all PV/store reads of jt-1 consumed

        // stage V(jt) then K(jt+1)   (V older than K in the FIFO)
        #pragma unroll
        for (int i = 0; i < 2; ++i)
            gll16(vth + (size_t)(w * 16 + i * 8 + srow) * S_LEN + jt * 64 + sblk * 8,
                  &Vt[(w * 16 + i * 8) * 64]);
        if (jt + 1 < nt) {
            #pragma unroll
            for (int i = 0; i < 2; ++i)
                gll16(kh + (size_t)((jt + 1) * 64 + w * 16 + i * 8 + srow) * HD + sblk * 8,
                      &Ks[(buf ^ 1) * 4096 + (w * 16 + i * 8) * 64]);
        }

        floatx4 sf[4] = {};
        #pragma unroll
        for (int ks = 0; ks < 2; ++ks) {
            short8 kb[4];
            #pragma unroll
            for (int c = 0; c < 4; ++c) {
                const int r = c * 16 + l15;
                kb[c] = *(const short8*)&Ks[buf * 4096 + r * 64
                                            + (((ks * 4 + l4) ^ (r & 7)) << 3)];
            }
            #pragma unroll
            for (int c = 0; c < 4; ++c)
                sf[c] = __builtin_amdgcn_mfma_f32_16x16x32_bf16(qa[ks], kb[c], sf[c], 0, 0, 0);
        }

        const int rbase = row0 + w * 16;
        const bool full = (jt * 64 + 63 <= rbase);
        #pragma unroll
        for (int c = 0; c < 4; ++c) {
            const int jcol = jt * 64 + c * 16 + l15;
            #pragma unroll
            for (int reg = 0; reg < 4; ++reg) {
                const int rl = w * 16 + l4 * 4 + reg;
                float p = exp2f(fmaf(sf[c][reg], C2, nl2[reg]));
                if (!full && jcol > rbase + l4 * 4 + reg) p = 0.f;
                Ps[rl * 88 + c * 16 + l15] = f2b(p);
            }
        }
        if (jt + 1 < nt) {
            // [St4, V2, K2] -> retire V (and >1-iter-old stores); K stays in flight
            asm volatile("s_waitcnt vmcnt(2) lgkmcnt(0)" ::: "memory");
        } else {
            asm volatile("s_waitcnt vmcnt(0) lgkmcnt(0)" ::: "memory");
        }
        __builtin_amdgcn_s_barrier();      // C: Ps visible, Vt landed

        // PV MFMA first ...
        #pragma unroll
        for (int ks = 0; ks < 2; ++ks) {
            const short8 pa = *(const short8*)&Ps[(w * 16 + l15) * 88 + ks * 32 + l4 * 8];
            #pragma unroll
            for (int c = 0; c < 4; ++c) {
                const int r = c * 16 + l15;
                const short8 vb = *(const short8*)&Vt[r * 64
                                                     + (((ks * 4 + l4) ^ (r & 7)) << 3)];
                o[c] = __builtin_amdgcn_mfma_f32_16x16x32_bf16(pa, vb, o[c], 0, 0, 0);
            }
        }

        // ... then NT stores (youngest VMEM ops; drain off the critical path)
        #pragma unroll
        for (int i2 = 0; i2 < 4; ++i2) {
            const int idx = tid + i2 * 256;
            const int r = idx >> 4, c4 = (idx & 15) * 4;
            const ushort4 pb = *(const ushort4*)&Ps[r * 88 + c4];
            floatx4 pf;
            pf[0] = b2f(pb.x); pf[1] = b2f(pb.y); pf[2] = b2f(pb.z); pf[3] = b2f(pb.w);
            __builtin_nontemporal_store(
                pf, (floatx4*)(attnh + (size_t)(row0 + r) * S_LEN + jt * 64 + c4));
        }
    }

    // context out (bf16, [B, S, H*64])
    const int b = bh >> 4, h = bh & 15;
    #pragma unroll
    for (int c = 0; c < 4; ++c)
        #pragma unroll
        for (int reg = 0; reg < 4; ++reg) {
            const int gr = row0 + w * 16 + l4 * 4 + reg;
            const int d = c * 16 + l15;
            ctx[((size_t)b * S_LEN + gr) * DMODEL + h * HD + d] = f2b(o[c][reg]);
        }

    // zero-fill strictly-above-diagonal tiles (nontemporal)
    const floatx4 z4 = {0.f, 0.f, 0.f, 0.f};
    for (int jt = nt; jt < S_LEN / 64; ++jt) {
        #pragma unroll
        for (int i = 0; i < 4; ++i) {
            const int idx = tid + i * 256;
            const int r = idx >> 4, off = (idx & 15) * 4;
            __builtin_nontemporal_store(
                z4, (floatx4*)(attnh + (size_t)(row0 + r) * S_LEN + jt * 64 + off));
        }
    }
}

// ---------------------------------------------------------------------------
extern "C" void kernel_launch(void* const* d_in, const int* in_sizes, int n_in,
                              void* d_out, int out_size, void* d_ws, size_t ws_size,
                              hipStream_t stream)
{
    const float* Q  = (const float*)d_in[0];
    const float* K  = (const float*)d_in[1];
    const float* V  = (const float*)d_in[2];
    const float* Wq = (const float*)d_in[4];
    const float* bq = (const float*)d_in[5];
    const float* Wk = (const float*)d_in[6];
    const float* bk = (const float*)d_in[7];
    const float* Wv = (const float*)d_in[8];
    const float* bv = (const float*)d_in[9];
    const float* Wo = (const float*)d_in[10];
    const float* bo = (const float*)d_in[11];

    float* out  = (float*)d_out;
    float* attn = out + (size_t)NBATCH * S_LEN * DMODEL;

    const size_t per = (size_t)NBATCH * S_LEN * DMODEL;
    const size_t wsz = (size_t)DMODEL * DMODEL;
    unsigned short* Xq  = (unsigned short*)d_ws;
    unsigned short* Xk  = Xq + per;
    unsigned short* Xv  = Xk + per;
    unsigned short* Wtq = Xv + per;
    unsigned short* Wtk = Wtq + wsz;
    unsigned short* Wtv = Wtk + wsz;
    unsigned short* Wto = Wtv + wsz;
    unsigned short* qhw = Wto + wsz;
    unsigned short* khw = qhw + per;
    unsigned short* vhw = khw + per;   // V transposed: [B,H,64,S]
    unsigned short* ctx = vhw + per;

    const int n4 = (int)(per / 4);
    convert_bf16<<<dim3((n4 + 255) / 256, 1, 3), 256, 0, stream>>>(
        Q, K, V, Xq, Xk, Xv, n4);
    transpose_w<<<dim3(16, 16, 4), 256, 0, stream>>>(Wq, Wk, Wv, Wo, Wtq, Wtk, Wtv, Wto);

    gemm_qkv<<<dim3(DMODEL / 128, (NBATCH * S_LEN) / 128, 3), 256, 0, stream>>>(
        Xq, Xk, Xv, Wtq, Wtk, Wtv, bq, bk, bv, qhw, khw, vhw);

    attn_mfma<<<1024, 256, 0, stream>>>(qhw, khw, vhw, attn, ctx);

    gemm_out<<<dim3(DMODEL / 64, (NBATCH * S_LEN) / 128), 256, 0, stream>>>(
        ctx, Wto, bo, out);
}

// Round 17
// 229.208 us; speedup vs baseline: 1.1260x; 1.0006x over previous
//
#include <hip/hip_runtime.h>
#include <math.h>

#define S_LEN 2048
#define DMODEL 1024
#define NHEAD 16
#define HD 64
#define NBATCH 2

using short8  = __attribute__((ext_vector_type(8))) short;
using ushort8 = __attribute__((ext_vector_type(8))) unsigned short;
using floatx4 = __attribute__((ext_vector_type(4))) float;

__device__ __forceinline__ unsigned short f2b(float f) {
    unsigned int u = __float_as_uint(f);
    unsigned int r = (u + 0x7FFFu + ((u >> 16) & 1u)) >> 16;
    return (unsigned short)r;
}
// fast 2-op bf16 round (round-half-up): used on the attn hot path
__device__ __forceinline__ unsigned short f2bf(float f) {
    return (unsigned short)((__float_as_uint(f) + 0x8000u) >> 16);
}
__device__ __forceinline__ float b2f(unsigned short b) {
    return __uint_as_float(((unsigned int)b) << 16);
}

// async global->LDS, 16B per lane; LDS dest = wave-uniform base + lane*16
__device__ __forceinline__ void gll16(const void* g, void* l) {
    __builtin_amdgcn_global_load_lds(
        (const __attribute__((address_space(1))) unsigned int*)g,
        (__attribute__((address_space(3))) unsigned int*)l, 16, 0, 0);
}

#define C2_SCALE 0.18033688011112042f   // 0.125 * log2(e), folded into Wq/bq

// ---------------------------------------------------------------------------
// fp32 -> bf16 convert; z selects Q/K/V
// ---------------------------------------------------------------------------
__global__ __launch_bounds__(256)
void convert_bf16(const float* __restrict__ S0, const float* __restrict__ S1,
                  const float* __restrict__ S2,
                  unsigned short* __restrict__ D0, unsigned short* __restrict__ D1,
                  unsigned short* __restrict__ D2, int n4)
{
    const float* src = (blockIdx.z == 0) ? S0 : (blockIdx.z == 1) ? S1 : S2;
    unsigned short* dst = (blockIdx.z == 0) ? D0 : (blockIdx.z == 1) ? D1 : D2;
    int i = blockIdx.x * 256 + threadIdx.x;
    if (i < n4) {
        float4 v = ((const float4*)src)[i];
        ushort4 o;
        o.x = f2b(v.x); o.y = f2b(v.y); o.z = f2b(v.z); o.w = f2b(v.w);
        ((ushort4*)dst)[i] = o;
    }
}

// ---------------------------------------------------------------------------
// W transpose + bf16. z==0 (Wq): values scaled by C2 BEFORE rounding (exact
// fp32 fold of the softmax scale); also emits bqs = bq*C2.
// ---------------------------------------------------------------------------
__global__ __launch_bounds__(256)
void transpose_w(const float* __restrict__ W0, const float* __restrict__ W1,
                 const float* __restrict__ W2, const float* __restrict__ W3,
                 unsigned short* __restrict__ T0, unsigned short* __restrict__ T1,
                 unsigned short* __restrict__ T2, unsigned short* __restrict__ T3,
                 const float* __restrict__ bq, float* __restrict__ bqs)
{
    __shared__ float t[64][65];
    const float* W; unsigned short* T;
    switch (blockIdx.z) {
        case 0: W = W0; T = T0; break;
        case 1: W = W1; T = T1; break;
        case 2: W = W2; T = T2; break;
        default: W = W3; T = T3; break;
    }
    const int tid = threadIdx.x;
    const int c0 = blockIdx.x * 64;
    const int r0 = blockIdx.y * 64;

    if (blockIdx.z == 0 && blockIdx.x == 0 && blockIdx.y == 0) {
        float4 b4 = *(const float4*)(bq + tid * 4);
        b4.x *= C2_SCALE; b4.y *= C2_SCALE; b4.z *= C2_SCALE; b4.w *= C2_SCALE;
        *(float4*)(bqs + tid * 4) = b4;
    }

    const float scl = (blockIdx.z == 0) ? C2_SCALE : 1.0f;

    #pragma unroll
    for (int i = 0; i < 4; ++i) {
        int c = tid + i * 256;
        int r = c >> 4, off = (c & 15) * 4;
        float4 v = *(const float4*)(W + (size_t)(r0 + r) * DMODEL + c0 + off);
        t[r][off + 0] = v.x; t[r][off + 1] = v.y;
        t[r][off + 2] = v.z; t[r][off + 3] = v.w;
    }
    __syncthreads();
    #pragma unroll
    for (int i = 0; i < 4; ++i) {
        int c = tid + i * 256;
        int n = c >> 4, off = (c & 15) * 4;
        ushort4 o;
        o.x = f2b(t[off + 0][n] * scl); o.y = f2b(t[off + 1][n] * scl);
        o.z = f2b(t[off + 2][n] * scl); o.w = f2b(t[off + 3][n] * scl);
        *(ushort4*)(T + (size_t)(c0 + n) * DMODEL + r0 + off) = o;
    }
}

// ---------------------------------------------------------------------------
// QKV GEMM, tile 128x128, BK=64, global_load_lds staging with XOR swizzle.
// z==0/1 (Q/K): head-major [B,H,S,64]. z==2 (V): TRANSPOSED [B,H,64,S].
// Q output is pre-scaled by C2 (via scaled Wq/bq).
// ---------------------------------------------------------------------------
__global__ __launch_bounds__(256)
void gemm_qkv(const unsigned short* __restrict__ X0, const unsigned short* __restrict__ X1,
              const unsigned short* __restrict__ X2,
              const unsigned short* __restrict__ W0, const unsigned short* __restrict__ W1,
              const unsigned short* __restrict__ W2,
              const float* __restrict__ b0, const float* __restrict__ b1,
              const float* __restrict__ b2,
              unsigned short* __restrict__ o0, unsigned short* __restrict__ o1,
              unsigned short* __restrict__ o2)
{
    __shared__ unsigned short Xs[128 * 64];
    __shared__ unsigned short Ws[128 * 64];

    const unsigned short* X  = (blockIdx.z == 0) ? X0 : (blockIdx.z == 1) ? X1 : X2;
    const unsigned short* Wt = (blockIdx.z == 0) ? W0 : (blockIdx.z == 1) ? W1 : W2;
    const float* bias        = (blockIdx.z == 0) ? b0 : (blockIdx.z == 1) ? b1 : b2;
    unsigned short* outp     = (blockIdx.z == 0) ? o0 : (blockIdx.z == 1) ? o1 : o2;

    const int tid = threadIdx.x;
    const int lane = tid & 63, w = tid >> 6;
    const int l15 = lane & 15, l4 = lane >> 4;
    const int wr = w >> 1, wc = w & 1;
    const int row0 = blockIdx.y * 128;
    const int col0 = blockIdx.x * 128;

    const int srow = lane >> 3;
    const int sblk = (lane & 7) ^ srow;

    floatx4 acc[4][4] = {};

    for (int k0 = 0; k0 < DMODEL; k0 += 64) {
        __syncthreads();
        #pragma unroll
        for (int i = 0; i < 4; ++i)
            gll16(X + (size_t)(row0 + w * 32 + i * 8 + srow) * DMODEL + k0 + sblk * 8,
                  &Xs[(w * 32 + i * 8) * 64]);
        #pragma unroll
        for (int i = 0; i < 4; ++i)
            gll16(Wt + (size_t)(col0 + w * 32 + i * 8 + srow) * DMODEL + k0 + sblk * 8,
                  &Ws[(w * 32 + i * 8) * 64]);
        asm volatile("s_waitcnt vmcnt(0)" ::: "memory");
        __syncthreads();

        #pragma unroll
        for (int ks = 0; ks < 2; ++ks) {
            short8 a[4], b[4];
            #pragma unroll
            for (int m = 0; m < 4; ++m) {
                const int r = wr * 64 + m * 16 + l15;
                a[m] = *(const short8*)&Xs[r * 64 + (((ks * 4 + l4) ^ (r & 7)) << 3)];
            }
            #pragma unroll
            for (int n = 0; n < 4; ++n) {
                const int r = wc * 64 + n * 16 + l15;
                b[n] = *(const short8*)&Ws[r * 64 + (((ks * 4 + l4) ^ (r & 7)) << 3)];
            }
            #pragma unroll
            for (int m = 0; m < 4; ++m)
                #pragma unroll
                for (int n = 0; n < 4; ++n)
                    acc[m][n] = __builtin_amdgcn_mfma_f32_16x16x32_bf16(
                        a[m], b[n], acc[m][n], 0, 0, 0);
        }
    }

    float bl[4];
    #pragma unroll
    for (int n = 0; n < 4; ++n)
        bl[n] = bias[col0 + wc * 64 + n * 16 + l15];

    if (blockIdx.z != 2) {
        #pragma unroll
        for (int m = 0; m < 4; ++m)
            #pragma unroll
            for (int n = 0; n < 4; ++n) {
                const int gc = col0 + wc * 64 + n * 16 + l15;
                const int h = gc >> 6, d = gc & 63;
                #pragma unroll
                for (int reg = 0; reg < 4; ++reg) {
                    const int gr = row0 + wr * 64 + m * 16 + l4 * 4 + reg;
                    const int bb = gr >> 11, s = gr & 2047;
                    outp[(((size_t)bb * NHEAD + h) * S_LEN + s) * HD + d] =
                        f2b(acc[m][n][reg] + bl[n]);
                }
            }
    } else {
        #pragma unroll
        for (int m = 0; m < 4; ++m)
            #pragma unroll
            for (int n = 0; n < 4; ++n) {
                const int gc = col0 + wc * 64 + n * 16 + l15;
                const int h = gc >> 6, d = gc & 63;
                const int s0 = row0 + wr * 64 + m * 16 + l4 * 4;
                const int bb = s0 >> 11, sr = s0 & 2047;
                ushort4 pk;
                pk.x = f2b(acc[m][n][0] + bl[n]);
                pk.y = f2b(acc[m][n][1] + bl[n]);
                pk.z = f2b(acc[m][n][2] + bl[n]);
                pk.w = f2b(acc[m][n][3] + bl[n]);
                *(ushort4*)(outp + (((size_t)bb * NHEAD + h) * HD + d) * S_LEN + sr) = pk;
            }
    }
}

// ---------------------------------------------------------------------------
// Output projection GEMM, tile 128x64 -> grid (16,32)=512 wg = 2 blocks/CU.
// ---------------------------------------------------------------------------
__global__ __launch_bounds__(256)
void gemm_out(const unsigned short* __restrict__ X, const unsigned short* __restrict__ Wt,
              const float* __restrict__ bias, float* __restrict__ out)
{
    __shared__ unsigned short Xs[128 * 64];
    __shared__ unsigned short Ws[64 * 64];

    const int tid = threadIdx.x;
    const int lane = tid & 63, w = tid >> 6;
    const int l15 = lane & 15, l4 = lane >> 4;
    const int wr = w >> 1, wc = w & 1;
    const int row0 = blockIdx.y * 128;
    const int col0 = blockIdx.x * 64;

    const int srow = lane >> 3;
    const int sblk = (lane & 7) ^ srow;

    floatx4 acc[4][2] = {};

    for (int k0 = 0; k0 < DMODEL; k0 += 64) {
        __syncthreads();
        #pragma unroll
        for (int i = 0; i < 4; ++i)
            gll16(X + (size_t)(row0 + w * 32 + i * 8 + srow) * DMODEL + k0 + sblk * 8,
                  &Xs[(w * 32 + i * 8) * 64]);
        #pragma unroll
        for (int i = 0; i < 2; ++i)
            gll16(Wt + (size_t)(col0 + w * 16 + i * 8 + srow) * DMODEL + k0 + sblk * 8,
                  &Ws[(w * 16 + i * 8) * 64]);
        asm volatile("s_waitcnt vmcnt(0)" ::: "memory");
        __syncthreads();

        #pragma unroll
        for (int ks = 0; ks < 2; ++ks) {
            short8 a[4], b[2];
            #pragma unroll
            for (int m = 0; m < 4; ++m) {
                const int r = wr * 64 + m * 16 + l15;
                a[m] = *(const short8*)&Xs[r * 64 + (((ks * 4 + l4) ^ (r & 7)) << 3)];
            }
            #pragma unroll
            for (int n = 0; n < 2; ++n) {
                const int r = wc * 32 + n * 16 + l15;
                b[n] = *(const short8*)&Ws[r * 64 + (((ks * 4 + l4) ^ (r & 7)) << 3)];
            }
            #pragma unroll
            for (int m = 0; m < 4; ++m)
                #pragma unroll
                for (int n = 0; n < 2; ++n)
                    acc[m][n] = __builtin_amdgcn_mfma_f32_16x16x32_bf16(
                        a[m], b[n], acc[m][n], 0, 0, 0);
        }
    }

    float bl[2];
    #pragma unroll
    for (int n = 0; n < 2; ++n)
        bl[n] = bias[col0 + wc * 32 + n * 16 + l15];

    #pragma unroll
    for (int m = 0; m < 4; ++m)
        #pragma unroll
        for (int n = 0; n < 2; ++n) {
            const int gc = col0 + wc * 32 + n * 16 + l15;
            #pragma unroll
            for (int reg = 0; reg < 4; ++reg) {
                const int gr = row0 + wr * 64 + m * 16 + l4 * 4 + reg;
                out[(size_t)gr * DMODEL + gc] = acc[m][n][reg] + bl[n];
            }
        }
}

// ---------------------------------------------------------------------------
// Attention (R15 structure). Changes: Q pre-scaled (no *C2 per element;
// pass-2 exponent is an add), 2-op bf16 pack on the Ps hot path.
// ---------------------------------------------------------------------------
__global__ __launch_bounds__(256)
void attn_mfma(const unsigned short* __restrict__ qg, const unsigned short* __restrict__ kg,
               const unsigned short* __restrict__ vtg, float* __restrict__ attn,
               unsigned short* __restrict__ ctx)
{
    __shared__ unsigned short Ks[2 * 64 * 64];
    __shared__ unsigned short Vt[64 * 64];
    __shared__ unsigned short Ps[64 * 88];

    const int tid = threadIdx.x;
    const int lane = tid & 63, w = tid >> 6;
    const int l15 = lane & 15, l4 = lane >> 4;

    const int i0 = blockIdx.x;
    const int local = i0 >> 3;
    const int bh = (i0 & 7) * 4 + (local & 3);
    const int qx = local >> 2;
    const int qb = (bh & 1) ? (31 - qx) : qx;
    const int row0 = qb * 64;

    const int srow = lane >> 3;
    const int sblk = (lane & 7) ^ srow;

    const unsigned short* qh = qg + (size_t)bh * S_LEN * HD;
    const unsigned short* kh = kg + (size_t)bh * S_LEN * HD;
    const unsigned short* vth = vtg + (size_t)bh * HD * S_LEN;   // [d][s]
    float* attnh = attn + (size_t)bh * S_LEN * S_LEN;

    short8 qa[2];
    #pragma unroll
    for (int ks = 0; ks < 2; ++ks)
        qa[ks] = *(const short8*)(qh + (size_t)(row0 + w * 16 + l15) * HD + ks * 32 + l4 * 8);

    const int nt = qb + 1;

    // ---- pass 1: row sums; K dbuf, raw barriers + counted vmcnt ----
    #pragma unroll
    for (int i = 0; i < 2; ++i)
        gll16(kh + (size_t)(w * 16 + i * 8 + srow) * HD + sblk * 8,
              &Ks[(w * 16 + i * 8) * 64]);

    float lsum[4] = {};
    for (int jt = 0; jt < nt; ++jt) {
        const int cur = jt & 1;
        __builtin_amdgcn_s_barrier();      // A: prev reads of Ks[cur^1] consumed
        if (jt + 1 < nt) {
            #pragma unroll
            for (int i = 0; i < 2; ++i)
                gll16(kh + (size_t)((jt + 1) * 64 + w * 16 + i * 8 + srow) * HD + sblk * 8,
                      &Ks[(cur ^ 1) * 4096 + (w * 16 + i * 8) * 64]);
            asm volatile("s_waitcnt vmcnt(2)" ::: "memory");   // K(jt) landed
        } else {
            asm volatile("s_waitcnt vmcnt(0)" ::: "memory");
        }
        __builtin_amdgcn_s_barrier();      // B: K(jt) visible to all waves

        floatx4 sf[4] = {};
        #pragma unroll
        for (int ks = 0; ks < 2; ++ks) {
            short8 kb[4];
            #pragma unroll
            for (int c = 0; c < 4; ++c) {
                const int r = c * 16 + l15;
                kb[c] = *(const short8*)&Ks[cur * 4096 + r * 64
                                            + (((ks * 4 + l4) ^ (r & 7)) << 3)];
            }
            #pragma unroll
            for (int c = 0; c < 4; ++c)
                sf[c] = __builtin_amdgcn_mfma_f32_16x16x32_bf16(qa[ks], kb[c], sf[c], 0, 0, 0);
        }

        const int rbase = row0 + w * 16;
        if (jt * 64 + 63 <= rbase) {
            #pragma unroll
            for (int c = 0; c < 4; ++c)
                #pragma unroll
                for (int reg = 0; reg < 4; ++reg)
                    lsum[reg] += exp2f(sf[c][reg]);
        } else {
            #pragma unroll
            for (int c = 0; c < 4; ++c) {
                const int jcol = jt * 64 + c * 16 + l15;
                #pragma unroll
                for (int reg = 0; reg < 4; ++reg) {
                    const int grow = rbase + l4 * 4 + reg;
                    lsum[reg] += (jcol <= grow) ? exp2f(sf[c][reg]) : 0.f;
                }
            }
        }
    }

    float nl2[4];
    #pragma unroll
    for (int reg = 0; reg < 4; ++reg) {
        float s = lsum[reg];
        #pragma unroll
        for (int off = 1; off < 16; off <<= 1)
            s += __shfl_xor(s, off);
        nl2[reg] = -__log2f(s);
    }

    // ---- transition: full drain once, then prologue K(0) ----
    asm volatile("s_waitcnt vmcnt(0) lgkmcnt(0)" ::: "memory");
    __builtin_amdgcn_s_barrier();
    #pragma unroll
    for (int i = 0; i < 2; ++i)
        gll16(kh + (size_t)(w * 16 + i * 8 + srow) * HD + sblk * 8,
              &Ks[(w * 16 + i * 8) * 64]);

    // ---- pass 2: QK^T + P + PV; raw barriers, stores last ----
    floatx4 o[4] = {};
    for (int jt = 0; jt < nt; ++jt) {
        const int buf = jt & 1;
        if (jt == 0) {
            asm volatile("s_waitcnt vmcnt(0)" ::: "memory");
        } else {
            asm volatile("s_waitcnt vmcnt(4)" ::: "memory");
        }
        __builtin_amdgcn_s_barrier();      // B

        #pragma unroll
        for (int i = 0; i < 2; ++i)
            gll16(vth + (size_t)(w * 16 + i * 8 + srow) * S_LEN + jt * 64 + sblk * 8,
                  &Vt[(w * 16 + i * 8) * 64]);
        if (jt + 1 < nt) {
            #pragma unroll
            for (int i = 0; i < 2; ++i)
                gll16(kh + (size_t)((jt + 1) * 64 + w * 16 + i * 8 + srow) * HD + sblk * 8,
                      &Ks[(buf ^ 1) * 4096 + (w * 16 + i * 8) * 64]);
        }

        floatx4 sf[4] = {};
        #pragma unroll
        for (int ks = 0; ks < 2; ++ks) {
            short8 kb[4];
            #pragma unroll
            for (int c = 0; c < 4; ++c) {
                const int r = c * 16 + l15;
                kb[c] = *(const short8*)&Ks[buf * 4096 + r * 64
                                            + (((ks * 4 + l4) ^ (r & 7)) << 3)];
            }
            #pragma unroll
            for (int c = 0; c < 4; ++c)
                sf[c] = __builtin_amdgcn_mfma_f32_16x16x32_bf16(qa[ks], kb[c], sf[c], 0, 0, 0);
        }

        const int rbase = row0 + w * 16;
        const bool full = (jt * 64 + 63 <= rbase);
        #pragma unroll
        for (int c = 0; c < 4; ++c) {
            const int jcol = jt * 64 + c * 16 + l15;
            #pragma unroll
            for (int reg = 0; reg < 4; ++reg) {
                const int rl = w * 16 + l4 * 4 + reg;
                float p = exp2f(sf[c][reg] + nl2[reg]);
                if (!full && jcol > rbase + l4 * 4 + reg) p = 0.f;
                Ps[rl * 88 + c * 16 + l15] = f2bf(p);
            }
        }
        if (jt + 1 < nt) {
            asm volatile("s_waitcnt vmcnt(2) lgkmcnt(0)" ::: "memory");
        } else {
            asm volatile("s_waitcnt vmcnt(0) lgkmcnt(0)" ::: "memory");
        }
        __builtin_amdgcn_s_barrier();      // C: Ps visible, Vt landed

        // PV MFMA first ...
        #pragma unroll
        for (int ks = 0; ks < 2; ++ks) {
            const short8 pa = *(const short8*)&Ps[(w * 16 + l15) * 88 + ks * 32 + l4 * 8];
            #pragma unroll
            for (int c = 0; c < 4; ++c) {
                const int r = c * 16 + l15;
                const short8 vb = *(const short8*)&Vt[r * 64
                                                     + (((ks * 4 + l4) ^ (r & 7)) << 3)];
                o[c] = __builtin_amdgcn_mfma_f32_16x16x32_bf16(pa, vb, o[c], 0, 0, 0);
            }
        }

        // ... then NT stores (youngest VMEM ops)
        #pragma unroll
        for (int i2 = 0; i2 < 4; ++i2) {
            const int idx = tid + i2 * 256;
            const int r = idx >> 4, c4 = (idx & 15) * 4;
            const ushort4 pb = *(const ushort4*)&Ps[r * 88 + c4];
            floatx4 pf;
            pf[0] = b2f(pb.x); pf[1] = b2f(pb.y); pf[2] = b2f(pb.z); pf[3] = b2f(pb.w);
            __builtin_nontemporal_store(
                pf, (floatx4*)(attnh + (size_t)(row0 + r) * S_LEN + jt * 64 + c4));
        }
    }

    // context out (bf16, [B, S, H*64])
    const int b = bh >> 4, h = bh & 15;
    #pragma unroll
    for (int c = 0; c < 4; ++c)
        #pragma unroll
        for (int reg = 0; reg < 4; ++reg) {
            const int gr = row0 + w * 16 + l4 * 4 + reg;
            const int d = c * 16 + l15;
            ctx[((size_t)b * S_LEN + gr) * DMODEL + h * HD + d] = f2b(o[c][reg]);
        }

    // zero-fill strictly-above-diagonal tiles (nontemporal)
    const floatx4 z4 = {0.f, 0.f, 0.f, 0.f};
    for (int jt = nt; jt < S_LEN / 64; ++jt) {
        #pragma unroll
        for (int i = 0; i < 4; ++i) {
            const int idx = tid + i * 256;
            const int r = idx >> 4, off = (idx & 15) * 4;
            __builtin_nontemporal_store(
                z4, (floatx4*)(attnh + (size_t)(row0 + r) * S_LEN + jt * 64 + off));
        }
    }
}

// ---------------------------------------------------------------------------
extern "C" void kernel_launch(void* const* d_in, const int* in_sizes, int n_in,
                              void* d_out, int out_size, void* d_ws, size_t ws_size,
                              hipStream_t stream)
{
    const float* Q  = (const float*)d_in[0];
    const float* K  = (const float*)d_in[1];
    const float* V  = (const float*)d_in[2];
    const float* Wq = (const float*)d_in[4];
    const float* bq = (const float*)d_in[5];
    const float* Wk = (const float*)d_in[6];
    const float* bk = (const float*)d_in[7];
    const float* Wv = (const float*)d_in[8];
    const float* bv = (const float*)d_in[9];
    const float* Wo = (const float*)d_in[10];
    const float* bo = (const float*)d_in[11];

    float* out  = (float*)d_out;
    float* attn = out + (size_t)NBATCH * S_LEN * DMODEL;

    const size_t per = (size_t)NBATCH * S_LEN * DMODEL;
    const size_t wsz = (size_t)DMODEL * DMODEL;
    unsigned short* Xq  = (unsigned short*)d_ws;
    unsigned short* Xk  = Xq + per;
    unsigned short* Xv  = Xk + per;
    unsigned short* Wtq = Xv + per;
    unsigned short* Wtk = Wtq + wsz;
    unsigned short* Wtv = Wtk + wsz;
    unsigned short* Wto = Wtv + wsz;
    unsigned short* qhw = Wto + wsz;
    unsigned short* khw = qhw + per;
    unsigned short* vhw = khw + per;   // V transposed: [B,H,64,S]
    unsigned short* ctx = vhw + per;
    float* bqs = (float*)(ctx + per);  // bq * C2

    const int n4 = (int)(per / 4);
    convert_bf16<<<dim3((n4 + 255) / 256, 1, 3), 256, 0, stream>>>(
        Q, K, V, Xq, Xk, Xv, n4);
    transpose_w<<<dim3(16, 16, 4), 256, 0, stream>>>(
        Wq, Wk, Wv, Wo, Wtq, Wtk, Wtv, Wto, bq, bqs);

    gemm_qkv<<<dim3(DMODEL / 128, (NBATCH * S_LEN) / 128, 3), 256, 0, stream>>>(
        Xq, Xk, Xv, Wtq, Wtk, Wtv, bqs, bk, bv, qhw, khw, vhw);

    attn_mfma<<<1024, 256, 0, stream>>>(qhw, khw, vhw, attn, ctx);

    gemm_out<<<dim3(DMODEL / 64, (NBATCH * S_LEN) / 128), 256, 0, stream>>>(
        ctx, Wto, bo, out);
}

// Round 18
// 224.437 us; speedup vs baseline: 1.1500x; 1.0213x over previous
//
#include <hip/hip_runtime.h>
#include <math.h>

#define S_LEN 2048
#define DMODEL 1024
#define NHEAD 16
#define HD 64
#define NBATCH 2

using short8  = __attribute__((ext_vector_type(8))) short;
using ushort8 = __attribute__((ext_vector_type(8))) unsigned short;
using floatx4 = __attribute__((ext_vector_type(4))) float;

__device__ __forceinline__ unsigned short f2b(float f) {
    unsigned int u = __float_as_uint(f);
    unsigned int r = (u + 0x7FFFu + ((u >> 16) & 1u)) >> 16;
    return (unsigned short)r;
}
// fast 2-op bf16 round (round-half-up): attn hot path
__device__ __forceinline__ unsigned short f2bf(float f) {
    return (unsigned short)((__float_as_uint(f) + 0x8000u) >> 16);
}
__device__ __forceinline__ float b2f(unsigned short b) {
    return __uint_as_float(((unsigned int)b) << 16);
}

// async global->LDS, 16B per lane; LDS dest = wave-uniform base + lane*16
__device__ __forceinline__ void gll16(const void* g, void* l) {
    __builtin_amdgcn_global_load_lds(
        (const __attribute__((address_space(1))) unsigned int*)g,
        (__attribute__((address_space(3))) unsigned int*)l, 16, 0, 0);
}

#define C2_SCALE 0.18033688011112042f   // 0.125 * log2(e), folded into Wq/bq

// ---------------------------------------------------------------------------
__global__ __launch_bounds__(256)
void convert_bf16(const float* __restrict__ S0, const float* __restrict__ S1,
                  const float* __restrict__ S2,
                  unsigned short* __restrict__ D0, unsigned short* __restrict__ D1,
                  unsigned short* __restrict__ D2, int n4)
{
    const float* src = (blockIdx.z == 0) ? S0 : (blockIdx.z == 1) ? S1 : S2;
    unsigned short* dst = (blockIdx.z == 0) ? D0 : (blockIdx.z == 1) ? D1 : D2;
    int i = blockIdx.x * 256 + threadIdx.x;
    if (i < n4) {
        float4 v = ((const float4*)src)[i];
        ushort4 o;
        o.x = f2b(v.x); o.y = f2b(v.y); o.z = f2b(v.z); o.w = f2b(v.w);
        ((ushort4*)dst)[i] = o;
    }
}

// ---------------------------------------------------------------------------
// W transpose + bf16. z==0 (Wq): scaled by C2 before rounding; emits bqs.
// ---------------------------------------------------------------------------
__global__ __launch_bounds__(256)
void transpose_w(const float* __restrict__ W0, const float* __restrict__ W1,
                 const float* __restrict__ W2, const float* __restrict__ W3,
                 unsigned short* __restrict__ T0, unsigned short* __restrict__ T1,
                 unsigned short* __restrict__ T2, unsigned short* __restrict__ T3,
                 const float* __restrict__ bq, float* __restrict__ bqs)
{
    __shared__ float t[64][65];
    const float* W; unsigned short* T;
    switch (blockIdx.z) {
        case 0: W = W0; T = T0; break;
        case 1: W = W1; T = T1; break;
        case 2: W = W2; T = T2; break;
        default: W = W3; T = T3; break;
    }
    const int tid = threadIdx.x;
    const int c0 = blockIdx.x * 64;
    const int r0 = blockIdx.y * 64;

    if (blockIdx.z == 0 && blockIdx.x == 0 && blockIdx.y == 0) {
        float4 b4 = *(const float4*)(bq + tid * 4);
        b4.x *= C2_SCALE; b4.y *= C2_SCALE; b4.z *= C2_SCALE; b4.w *= C2_SCALE;
        *(float4*)(bqs + tid * 4) = b4;
    }

    const float scl = (blockIdx.z == 0) ? C2_SCALE : 1.0f;

    #pragma unroll
    for (int i = 0; i < 4; ++i) {
        int c = tid + i * 256;
        int r = c >> 4, off = (c & 15) * 4;
        float4 v = *(const float4*)(W + (size_t)(r0 + r) * DMODEL + c0 + off);
        t[r][off + 0] = v.x; t[r][off + 1] = v.y;
        t[r][off + 2] = v.z; t[r][off + 3] = v.w;
    }
    __syncthreads();
    #pragma unroll
    for (int i = 0; i < 4; ++i) {
        int c = tid + i * 256;
        int n = c >> 4, off = (c & 15) * 4;
        ushort4 o;
        o.x = f2b(t[off + 0][n] * scl); o.y = f2b(t[off + 1][n] * scl);
        o.z = f2b(t[off + 2][n] * scl); o.w = f2b(t[off + 3][n] * scl);
        *(ushort4*)(T + (size_t)(c0 + n) * DMODEL + r0 + off) = o;
    }
}

// ---------------------------------------------------------------------------
// QKV GEMM, tile 128x128, BK=64, gll16 staging with XOR swizzle.
// z==0/1 (Q/K): head-major [B,H,S,64]. z==2 (V): TRANSPOSED [B,H,64,S].
// ---------------------------------------------------------------------------
__global__ __launch_bounds__(256)
void gemm_qkv(const unsigned short* __restrict__ X0, const unsigned short* __restrict__ X1,
              const unsigned short* __restrict__ X2,
              const unsigned short* __restrict__ W0, const unsigned short* __restrict__ W1,
              const unsigned short* __restrict__ W2,
              const float* __restrict__ b0, const float* __restrict__ b1,
              const float* __restrict__ b2,
              unsigned short* __restrict__ o0, unsigned short* __restrict__ o1,
              unsigned short* __restrict__ o2)
{
    __shared__ unsigned short Xs[128 * 64];
    __shared__ unsigned short Ws[128 * 64];

    const unsigned short* X  = (blockIdx.z == 0) ? X0 : (blockIdx.z == 1) ? X1 : X2;
    const unsigned short* Wt = (blockIdx.z == 0) ? W0 : (blockIdx.z == 1) ? W1 : W2;
    const float* bias        = (blockIdx.z == 0) ? b0 : (blockIdx.z == 1) ? b1 : b2;
    unsigned short* outp     = (blockIdx.z == 0) ? o0 : (blockIdx.z == 1) ? o1 : o2;

    const int tid = threadIdx.x;
    const int lane = tid & 63, w = tid >> 6;
    const int l15 = lane & 15, l4 = lane >> 4;
    const int wr = w >> 1, wc = w & 1;
    const int row0 = blockIdx.y * 128;
    const int col0 = blockIdx.x * 128;

    const int srow = lane >> 3;
    const int sblk = (lane & 7) ^ srow;

    floatx4 acc[4][4] = {};

    for (int k0 = 0; k0 < DMODEL; k0 += 64) {
        __syncthreads();
        #pragma unroll
        for (int i = 0; i < 4; ++i)
            gll16(X + (size_t)(row0 + w * 32 + i * 8 + srow) * DMODEL + k0 + sblk * 8,
                  &Xs[(w * 32 + i * 8) * 64]);
        #pragma unroll
        for (int i = 0; i < 4; ++i)
            gll16(Wt + (size_t)(col0 + w * 32 + i * 8 + srow) * DMODEL + k0 + sblk * 8,
                  &Ws[(w * 32 + i * 8) * 64]);
        asm volatile("s_waitcnt vmcnt(0)" ::: "memory");
        __syncthreads();

        #pragma unroll
        for (int ks = 0; ks < 2; ++ks) {
            short8 a[4], b[4];
            #pragma unroll
            for (int m = 0; m < 4; ++m) {
                const int r = wr * 64 + m * 16 + l15;
                a[m] = *(const short8*)&Xs[r * 64 + (((ks * 4 + l4) ^ (r & 7)) << 3)];
            }
            #pragma unroll
            for (int n = 0; n < 4; ++n) {
                const int r = wc * 64 + n * 16 + l15;
                b[n] = *(const short8*)&Ws[r * 64 + (((ks * 4 + l4) ^ (r & 7)) << 3)];
            }
            #pragma unroll
            for (int m = 0; m < 4; ++m)
                #pragma unroll
                for (int n = 0; n < 4; ++n)
                    acc[m][n] = __builtin_amdgcn_mfma_f32_16x16x32_bf16(
                        a[m], b[n], acc[m][n], 0, 0, 0);
        }
    }

    float bl[4];
    #pragma unroll
    for (int n = 0; n < 4; ++n)
        bl[n] = bias[col0 + wc * 64 + n * 16 + l15];

    if (blockIdx.z != 2) {
        #pragma unroll
        for (int m = 0; m < 4; ++m)
            #pragma unroll
            for (int n = 0; n < 4; ++n) {
                const int gc = col0 + wc * 64 + n * 16 + l15;
                const int h = gc >> 6, d = gc & 63;
                #pragma unroll
                for (int reg = 0; reg < 4; ++reg) {
                    const int gr = row0 + wr * 64 + m * 16 + l4 * 4 + reg;
                    const int bb = gr >> 11, s = gr & 2047;
                    outp[(((size_t)bb * NHEAD + h) * S_LEN + s) * HD + d] =
                        f2b(acc[m][n][reg] + bl[n]);
                }
            }
    } else {
        #pragma unroll
        for (int m = 0; m < 4; ++m)
            #pragma unroll
            for (int n = 0; n < 4; ++n) {
                const int gc = col0 + wc * 64 + n * 16 + l15;
                const int h = gc >> 6, d = gc & 63;
                const int s0 = row0 + wr * 64 + m * 16 + l4 * 4;
                const int bb = s0 >> 11, sr = s0 & 2047;
                ushort4 pk;
                pk.x = f2b(acc[m][n][0] + bl[n]);
                pk.y = f2b(acc[m][n][1] + bl[n]);
                pk.z = f2b(acc[m][n][2] + bl[n]);
                pk.w = f2b(acc[m][n][3] + bl[n]);
                *(ushort4*)(outp + (((size_t)bb * NHEAD + h) * HD + d) * S_LEN + sr) = pk;
            }
    }
}

// ---------------------------------------------------------------------------
// Output projection GEMM, tile 128x64 -> grid (16,32)=512 wg = 2 blocks/CU.
// ---------------------------------------------------------------------------
__global__ __launch_bounds__(256)
void gemm_out(const unsigned short* __restrict__ X, const unsigned short* __restrict__ Wt,
              const float* __restrict__ bias, float* __restrict__ out)
{
    __shared__ unsigned short Xs[128 * 64];
    __shared__ unsigned short Ws[64 * 64];

    const int tid = threadIdx.x;
    const int lane = tid & 63, w = tid >> 6;
    const int l15 = lane & 15, l4 = lane >> 4;
    const int wr = w >> 1, wc = w & 1;
    const int row0 = blockIdx.y * 128;
    const int col0 = blockIdx.x * 64;

    const int srow = lane >> 3;
    const int sblk = (lane & 7) ^ srow;

    floatx4 acc[4][2] = {};

    for (int k0 = 0; k0 < DMODEL; k0 += 64) {
        __syncthreads();
        #pragma unroll
        for (int i = 0; i < 4; ++i)
            gll16(X + (size_t)(row0 + w * 32 + i * 8 + srow) * DMODEL + k0 + sblk * 8,
                  &Xs[(w * 32 + i * 8) * 64]);
        #pragma unroll
        for (int i = 0; i < 2; ++i)
            gll16(Wt + (size_t)(col0 + w * 16 + i * 8 + srow) * DMODEL + k0 + sblk * 8,
                  &Ws[(w * 16 + i * 8) * 64]);
        asm volatile("s_waitcnt vmcnt(0)" ::: "memory");
        __syncthreads();

        #pragma unroll
        for (int ks = 0; ks < 2; ++ks) {
            short8 a[4], b[2];
            #pragma unroll
            for (int m = 0; m < 4; ++m) {
                const int r = wr * 64 + m * 16 + l15;
                a[m] = *(const short8*)&Xs[r * 64 + (((ks * 4 + l4) ^ (r & 7)) << 3)];
            }
            #pragma unroll
            for (int n = 0; n < 2; ++n) {
                const int r = wc * 32 + n * 16 + l15;
                b[n] = *(const short8*)&Ws[r * 64 + (((ks * 4 + l4) ^ (r & 7)) << 3)];
            }
            #pragma unroll
            for (int m = 0; m < 4; ++m)
                #pragma unroll
                for (int n = 0; n < 2; ++n)
                    acc[m][n] = __builtin_amdgcn_mfma_f32_16x16x32_bf16(
                        a[m], b[n], acc[m][n], 0, 0, 0);
        }
    }

    float bl[2];
    #pragma unroll
    for (int n = 0; n < 2; ++n)
        bl[n] = bias[col0 + wc * 32 + n * 16 + l15];

    #pragma unroll
    for (int m = 0; m < 4; ++m)
        #pragma unroll
        for (int n = 0; n < 2; ++n) {
            const int gc = col0 + wc * 32 + n * 16 + l15;
            #pragma unroll
            for (int reg = 0; reg < 4; ++reg) {
                const int gr = row0 + wr * 64 + m * 16 + l4 * 4 + reg;
                out[(size_t)gr * DMODEL + gc] = acc[m][n][reg] + bl[n];
            }
        }
}

// ---------------------------------------------------------------------------
// Attention. Change vs R16: P(jt-1) NT stores deferred to TOP of iter jt,
// issued AFTER V(jt)/K(jt+1) so stores are always YOUNGER than any waited-on
// load -> no wait ever forces store completion (vmcnt(6)/vmcnt(4) ledger).
// Stores/PV read only own-wave Ps rows (same-wave program order makes the
// deferred read of Ps(jt-1) before the Ps(jt) overwrite safe).
// ---------------------------------------------------------------------------
__global__ __launch_bounds__(256)
void attn_mfma(const unsigned short* __restrict__ qg, const unsigned short* __restrict__ kg,
               const unsigned short* __restrict__ vtg, float* __restrict__ attn,
               unsigned short* __restrict__ ctx)
{
    __shared__ unsigned short Ks[2 * 64 * 64];
    __shared__ unsigned short Vt[64 * 64];
    __shared__ unsigned short Ps[64 * 88];

    const int tid = threadIdx.x;
    const int lane = tid & 63, w = tid >> 6;
    const int l15 = lane & 15, l4 = lane >> 4;

    const int i0 = blockIdx.x;
    const int local = i0 >> 3;
    const int bh = (i0 & 7) * 4 + (local & 3);
    const int qx = local >> 2;
    const int qb = (bh & 1) ? (31 - qx) : qx;
    const int row0 = qb * 64;

    const int srow = lane >> 3;
    const int sblk = (lane & 7) ^ srow;

    const unsigned short* qh = qg + (size_t)bh * S_LEN * HD;
    const unsigned short* kh = kg + (size_t)bh * S_LEN * HD;
    const unsigned short* vth = vtg + (size_t)bh * HD * S_LEN;   // [d][s]
    float* attnh = attn + (size_t)bh * S_LEN * S_LEN;

    short8 qa[2];
    #pragma unroll
    for (int ks = 0; ks < 2; ++ks)
        qa[ks] = *(const short8*)(qh + (size_t)(row0 + w * 16 + l15) * HD + ks * 32 + l4 * 8);

    const int nt = qb + 1;

    // ---- pass 1: row sums; K dbuf, raw barriers + counted vmcnt ----
    #pragma unroll
    for (int i = 0; i < 2; ++i)
        gll16(kh + (size_t)(w * 16 + i * 8 + srow) * HD + sblk * 8,
              &Ks[(w * 16 + i * 8) * 64]);

    float lsum[4] = {};
    for (int jt = 0; jt < nt; ++jt) {
        const int cur = jt & 1;
        __builtin_amdgcn_s_barrier();
        if (jt + 1 < nt) {
            #pragma unroll
            for (int i = 0; i < 2; ++i)
                gll16(kh + (size_t)((jt + 1) * 64 + w * 16 + i * 8 + srow) * HD + sblk * 8,
                      &Ks[(cur ^ 1) * 4096 + (w * 16 + i * 8) * 64]);
            asm volatile("s_waitcnt vmcnt(2)" ::: "memory");
        } else {
            asm volatile("s_waitcnt vmcnt(0)" ::: "memory");
        }
        __builtin_amdgcn_s_barrier();

        floatx4 sf[4] = {};
        #pragma unroll
        for (int ks = 0; ks < 2; ++ks) {
            short8 kb[4];
            #pragma unroll
            for (int c = 0; c < 4; ++c) {
                const int r = c * 16 + l15;
                kb[c] = *(const short8*)&Ks[cur * 4096 + r * 64
                                            + (((ks * 4 + l4) ^ (r & 7)) << 3)];
            }
            #pragma unroll
            for (int c = 0; c < 4; ++c)
                sf[c] = __builtin_amdgcn_mfma_f32_16x16x32_bf16(qa[ks], kb[c], sf[c], 0, 0, 0);
        }

        const int rbase = row0 + w * 16;
        if (jt * 64 + 63 <= rbase) {
            #pragma unroll
            for (int c = 0; c < 4; ++c)
                #pragma unroll
                for (int reg = 0; reg < 4; ++reg)
                    lsum[reg] += exp2f(sf[c][reg]);
        } else {
            #pragma unroll
            for (int c = 0; c < 4; ++c) {
                const int jcol = jt * 64 + c * 16 + l15;
                #pragma unroll
                for (int reg = 0; reg < 4; ++reg) {
                    const int grow = rbase + l4 * 4 + reg;
                    lsum[reg] += (jcol <= grow) ? exp2f(sf[c][reg]) : 0.f;
                }
            }
        }
    }

    float nl2[4];
    #pragma unroll
    for (int reg = 0; reg < 4; ++reg) {
        float s = lsum[reg];
        #pragma unroll
        for (int off = 1; off < 16; off <<= 1)
            s += __shfl_xor(s, off);
        nl2[reg] = -__log2f(s);
    }

    // ---- transition ----
    asm volatile("s_waitcnt vmcnt(0) lgkmcnt(0)" ::: "memory");
    __builtin_amdgcn_s_barrier();
    #pragma unroll
    for (int i = 0; i < 2; ++i)
        gll16(kh + (size_t)(w * 16 + i * 8 + srow) * HD + sblk * 8,
              &Ks[(w * 16 + i * 8) * 64]);

    // ---- pass 2 ----
    floatx4 o[4] = {};
    for (int jt = 0; jt < nt; ++jt) {
        const int buf = jt & 1;
        // pre-B: retire K(jt); keep St(jt-1) (4 youngest). jt<=1: no stores old enough.
        if (jt <= 1) {
            asm volatile("s_waitcnt vmcnt(0)" ::: "memory");
        } else {
            asm volatile("s_waitcnt vmcnt(4)" ::: "memory");
        }
        __builtin_amdgcn_s_barrier();      // B: all PV(jt-1) done; K(jt) visible

        // stage V(jt), then K(jt+1)
        #pragma unroll
        for (int i = 0; i < 2; ++i)
            gll16(vth + (size_t)(w * 16 + i * 8 + srow) * S_LEN + jt * 64 + sblk * 8,
                  &Vt[(w * 16 + i * 8) * 64]);
        if (jt + 1 < nt) {
            #pragma unroll
            for (int i = 0; i < 2; ++i)
                gll16(kh + (size_t)((jt + 1) * 64 + w * 16 + i * 8 + srow) * HD + sblk * 8,
                      &Ks[(buf ^ 1) * 4096 + (w * 16 + i * 8) * 64]);
        }

        // deferred NT store of P(jt-1): own-wave rows, younger than V/K above
        if (jt >= 1) {
            #pragma unroll
            for (int i2 = 0; i2 < 4; ++i2) {
                const int idx = lane + i2 * 64;
                const int r = w * 16 + (idx >> 4), c4 = (idx & 15) * 4;
                const ushort4 pb = *(const ushort4*)&Ps[r * 88 + c4];
                floatx4 pf;
                pf[0] = b2f(pb.x); pf[1] = b2f(pb.y); pf[2] = b2f(pb.z); pf[3] = b2f(pb.w);
                __builtin_nontemporal_store(
                    pf, (floatx4*)(attnh + (size_t)(row0 + r) * S_LEN + (jt - 1) * 64 + c4));
            }
        }

        floatx4 sf[4] = {};
        #pragma unroll
        for (int ks = 0; ks < 2; ++ks) {
            short8 kb[4];
            #pragma unroll
            for (int c = 0; c < 4; ++c) {
                const int r = c * 16 + l15;
                kb[c] = *(const short8*)&Ks[buf * 4096 + r * 64
                                            + (((ks * 4 + l4) ^ (r & 7)) << 3)];
            }
            #pragma unroll
            for (int c = 0; c < 4; ++c)
                sf[c] = __builtin_amdgcn_mfma_f32_16x16x32_bf16(qa[ks], kb[c], sf[c], 0, 0, 0);
        }

        const int rbase = row0 + w * 16;
        const bool full = (jt * 64 + 63 <= rbase);
        #pragma unroll
        for (int c = 0; c < 4; ++c) {
            const int jcol = jt * 64 + c * 16 + l15;
            #pragma unroll
            for (int reg = 0; reg < 4; ++reg) {
                const int rl = w * 16 + l4 * 4 + reg;
                float p = exp2f(sf[c][reg] + nl2[reg]);
                if (!full && jcol > rbase + l4 * 4 + reg) p = 0.f;
                Ps[rl * 88 + c * 16 + l15] = f2bf(p);
            }
        }
        // post-Ps: retire V(jt) only (stores + K(jt+1) stay in flight)
        if (jt + 1 < nt) {
            if (jt == 0) {
                asm volatile("s_waitcnt vmcnt(2) lgkmcnt(0)" ::: "memory");   // [V,K]
            } else {
                asm volatile("s_waitcnt vmcnt(6) lgkmcnt(0)" ::: "memory");   // [.,V,K,St]
            }
        } else {
            if (jt == 0) {
                asm volatile("s_waitcnt vmcnt(0) lgkmcnt(0)" ::: "memory");
            } else {
                asm volatile("s_waitcnt vmcnt(4) lgkmcnt(0)" ::: "memory");   // keep St(jt-1)
            }
        }
        __builtin_amdgcn_s_barrier();      // C: Ps visible (own-wave), Vt landed

        // PV MFMA (pa = own-wave Ps rows)
        #pragma unroll
        for (int ks = 0; ks < 2; ++ks) {
            const short8 pa = *(const short8*)&Ps[(w * 16 + l15) * 88 + ks * 32 + l4 * 8];
            #pragma unroll
            for (int c = 0; c < 4; ++c) {
                const int r = c * 16 + l15;
                const short8 vb = *(const short8*)&Vt[r * 64
                                                     + (((ks * 4 + l4) ^ (r & 7)) << 3)];
                o[c] = __builtin_amdgcn_mfma_f32_16x16x32_bf16(pa, vb, o[c], 0, 0, 0);
            }
        }
    }

    // epilogue: store P(nt-1)
    {
        const int jt = nt - 1;
        #pragma unroll
        for (int i2 = 0; i2 < 4; ++i2) {
            const int idx = lane + i2 * 64;
            const int r = w * 16 + (idx >> 4), c4 = (idx & 15) * 4;
            const ushort4 pb = *(const ushort4*)&Ps[r * 88 + c4];
            floatx4 pf;
            pf[0] = b2f(pb.x); pf[1] = b2f(pb.y); pf[2] = b2f(pb.z); pf[3] = b2f(pb.w);
            __builtin_nontemporal_store(
                pf, (floatx4*)(attnh + (size_t)(row0 + r) * S_LEN + jt * 64 + c4));
        }
    }

    // context out (bf16, [B, S, H*64])
    const int b = bh >> 4, h = bh & 15;
    #pragma unroll
    for (int c = 0; c < 4; ++c)
        #pragma unroll
        for (int reg = 0; reg < 4; ++reg) {
            const int gr = row0 + w * 16 + l4 * 4 + reg;
            const int d = c * 16 + l15;
            ctx[((size_t)b * S_LEN + gr) * DMODEL + h * HD + d] = f2b(o[c][reg]);
        }

    // zero-fill strictly-above-diagonal tiles (nontemporal)
    const floatx4 z4 = {0.f, 0.f, 0.f, 0.f};
    for (int jt = nt; jt < S_LEN / 64; ++jt) {
        #pragma unroll
        for (int i = 0; i < 4; ++i) {
            const int idx = tid + i * 256;
            const int r = idx >> 4, off = (idx & 15) * 4;
            __builtin_nontemporal_store(
                z4, (floatx4*)(attnh + (size_t)(row0 + r) * S_LEN + jt * 64 + off));
        }
    }
}

// ---------------------------------------------------------------------------
extern "C" void kernel_launch(void* const* d_in, const int* in_sizes, int n_in,
                              void* d_out, int out_size, void* d_ws, size_t ws_size,
                              hipStream_t stream)
{
    const float* Q  = (const float*)d_in[0];
    const float* K  = (const float*)d_in[1];
    const float* V  = (const float*)d_in[2];
    const float* Wq = (const float*)d_in[4];
    const float* bq = (const float*)d_in[5];
    const float* Wk = (const float*)d_in[6];
    const float* bk = (const float*)d_in[7];
    const float* Wv = (const float*)d_in[8];
    const float* bv = (const float*)d_in[9];
    const float* Wo = (const float*)d_in[10];
    const float* bo = (const float*)d_in[11];

    float* out  = (float*)d_out;
    float* attn = out + (size_t)NBATCH * S_LEN * DMODEL;

    const size_t per = (size_t)NBATCH * S_LEN * DMODEL;
    const size_t wsz = (size_t)DMODEL * DMODEL;
    unsigned short* Xq  = (unsigned short*)d_ws;
    unsigned short* Xk  = Xq + per;
    unsigned short* Xv  = Xk + per;
    unsigned short* Wtq = Xv + per;
    unsigned short* Wtk = Wtq + wsz;
    unsigned short* Wtv = Wtk + wsz;
    unsigned short* Wto = Wtv + wsz;
    unsigned short* qhw = Wto + wsz;
    unsigned short* khw = qhw + per;
    unsigned short* vhw = khw + per;   // V transposed: [B,H,64,S]
    unsigned short* ctx = vhw + per;
    float* bqs = (float*)(ctx + per);  // bq * C2

    const int n4 = (int)(per / 4);
    convert_bf16<<<dim3((n4 + 255) / 256, 1, 3), 256, 0, stream>>>(
        Q, K, V, Xq, Xk, Xv, n4);
    transpose_w<<<dim3(16, 16, 4), 256, 0, stream>>>(
        Wq, Wk, Wv, Wo, Wtq, Wtk, Wtv, Wto, bq, bqs);

    gemm_qkv<<<dim3(DMODEL / 128, (NBATCH * S_LEN) / 128, 3), 256, 0, stream>>>(
        Xq, Xk, Xv, Wtq, Wtk, Wtv, bqs, bk, bv, qhw, khw, vhw);

    attn_mfma<<<1024, 256, 0, stream>>>(qhw, khw, vhw, attn, ctx);

    gemm_out<<<dim3(DMODEL / 64, (NBATCH * S_LEN) / 128), 256, 0, stream>>>(
        ctx, Wto, bo, out);
}